// Round 1
// baseline (502.570 us; speedup 1.0000x reference)
//
#include <hip/hip_runtime.h>
#include <stdint.h>

// MatrixAttentionFunc: b=2, NH=8, KD=HD=32, D=256, 64x64 spatial.
// P = w_proj @ x per pixel; row/col attention softmaxes; bilinear apply + v.
//
// ws layout (floats):
//   P      [2][1280][64*64]          @ 0         (10,485,760)
//   Rsoft  [bh][j(=h)][w][i]         @ 10485760  ( 4,194,304)  softmax over i
//   Csoft  [bh][h][jj][w]            @ 14680064  ( 4,194,304)  softmax over jj
//   Vt     [bh*32+d][j][i]           @ 18874368  ( 2,097,152)  transposed v
// total 20,971,520 floats = 83.9 MB

#define SCALE 0.17677669529663687f

__device__ __forceinline__ unsigned short f2bf(float f) {
  unsigned int b = __float_as_uint(f);
  b += 0x7fffu + ((b >> 16) & 1u);           // round-to-nearest-even
  return (unsigned short)(b >> 16);
}
__device__ __forceinline__ float bflo(unsigned int u) { return __uint_as_float(u << 16); }
__device__ __forceinline__ float bfhi(unsigned int u) { return __uint_as_float(u & 0xffff0000u); }
__device__ __forceinline__ uint2 pack4(float4 f) {
  uint2 r;
  r.x = (unsigned int)f2bf(f.x) | ((unsigned int)f2bf(f.y) << 16);
  r.y = (unsigned int)f2bf(f.z) | ((unsigned int)f2bf(f.w) << 16);
  return r;
}

// ---------------- Stage A: projection GEMM  P[b] = W(1280x256) @ X[b](256x4096)
__global__ __launch_bounds__(256, 2) void proj_gemm(const float* __restrict__ x,
                                                    const float* __restrict__ w,
                                                    float* __restrict__ p) {
  __shared__ float Wt[8][128];   // [k][m]
  __shared__ float Xt[8][128];   // [k][n]
  const int b  = blockIdx.z;
  const int m0 = blockIdx.y * 128;
  const int n0 = blockIdx.x * 128;
  const float* xb = x + (size_t)b * 256 * 4096;
  float* pb = p + (size_t)b * 1280 * 4096;
  const int t  = threadIdx.x;
  const int ty = t >> 4, tx = t & 15;

  float acc[8][8];
#pragma unroll
  for (int i = 0; i < 8; i++)
#pragma unroll
    for (int j = 0; j < 8; j++) acc[i][j] = 0.f;

  const int lrow = t >> 1;          // 0..127 (m)
  const int lkk  = (t & 1) * 4;     // 0 or 4 (k)
  const int xkr  = t >> 5;          // 0..7   (k)
  const int xcol = (t & 31) * 4;    // 0..124 (n)

  for (int k0 = 0; k0 < 256; k0 += 8) {
    float4 wv = *(const float4*)&w[(size_t)(m0 + lrow) * 256 + k0 + lkk];
    float4 xv = *(const float4*)&xb[(size_t)(k0 + xkr) * 4096 + n0 + xcol];
    Wt[lkk + 0][lrow] = wv.x;
    Wt[lkk + 1][lrow] = wv.y;
    Wt[lkk + 2][lrow] = wv.z;
    Wt[lkk + 3][lrow] = wv.w;
    *(float4*)&Xt[xkr][xcol] = xv;
    __syncthreads();
#pragma unroll
    for (int k = 0; k < 8; k++) {
      float av[8], bv[8];
      *(float4*)&av[0] = *(const float4*)&Wt[k][ty * 8];
      *(float4*)&av[4] = *(const float4*)&Wt[k][ty * 8 + 4];
      *(float4*)&bv[0] = *(const float4*)&Xt[k][tx * 8];
      *(float4*)&bv[4] = *(const float4*)&Xt[k][tx * 8 + 4];
#pragma unroll
      for (int i = 0; i < 8; i++)
#pragma unroll
        for (int j = 0; j < 8; j++)
          acc[i][j] = fmaf(av[i], bv[j], acc[i][j]);
    }
    __syncthreads();
  }
#pragma unroll
  for (int i = 0; i < 8; i++) {
    float* dst = &pb[(size_t)(m0 + ty * 8 + i) * 4096 + n0 + tx * 8];
    *(float4*)&dst[0] = *(float4*)&acc[i][0];
    *(float4*)&dst[4] = *(float4*)&acc[i][4];
  }
}

// ---------------- Stage B: row attention. block = bh*64 + w.
// S[i][j] = SCALE * sum_d rq[d,i,w]*rk[d,j,w]; softmax over i per j;
// write Rsoft[bh][j][w][i].
__global__ __launch_bounds__(256) void row_softmax(const float* __restrict__ p,
                                                   float* __restrict__ rsoft) {
  const int blk = blockIdx.x;
  const int w   = blk & 63;
  const int bh  = blk >> 6;
  const float* pb = p + (size_t)(bh >> 3) * 1280 * 4096 + (size_t)(bh & 7) * 160 * 4096;
  __shared__ float rq[32][64];
  __shared__ float rk[32][64];
  __shared__ float S[64][65];
  __shared__ float mJ[64], sJ[64];
  const int t = threadIdx.x;
#pragma unroll
  for (int rep = 0; rep < 8; rep++) {
    int idx = rep * 256 + t;
    int d = idx >> 6, i = idx & 63;
    rq[d][i] = pb[(size_t)d * 4096 + i * 64 + w];
    rk[d][i] = pb[(size_t)(32 + d) * 4096 + i * 64 + w];
  }
  __syncthreads();
  const int ti = (t >> 4) * 4, tj = (t & 15) * 4;
  float a2[4][4];
#pragma unroll
  for (int q = 0; q < 4; q++)
#pragma unroll
    for (int r = 0; r < 4; r++) a2[q][r] = 0.f;
  for (int d = 0; d < 32; d++) {
    float4 av = *(const float4*)&rq[d][ti];
    float4 bv = *(const float4*)&rk[d][tj];
    const float* ap = &av.x;
    const float* bp = &bv.x;
#pragma unroll
    for (int q = 0; q < 4; q++)
#pragma unroll
      for (int r = 0; r < 4; r++)
        a2[q][r] = fmaf(ap[q], bp[r], a2[q][r]);
  }
#pragma unroll
  for (int q = 0; q < 4; q++)
#pragma unroll
    for (int r = 0; r < 4; r++)
      S[ti + q][tj + r] = a2[q][r] * SCALE;
  __syncthreads();
  if (t < 64) {
    const int j = t;
    float m = -1e30f;
    for (int i = 0; i < 64; i++) m = fmaxf(m, S[i][j]);
    float s = 0.f;
    for (int i = 0; i < 64; i++) s += __expf(S[i][j] - m);
    mJ[j] = m;
    sJ[j] = 1.f / s;
  }
  __syncthreads();
  float* osl = rsoft + (size_t)bh * 64 * 4096;
  const int j = t >> 2, i0 = (t & 3) * 16;
  const float m = mJ[j], inv = sJ[j];
#pragma unroll
  for (int q4 = 0; q4 < 4; q4++) {
    float4 o;
    o.x = __expf(S[i0 + q4 * 4 + 0][j] - m) * inv;
    o.y = __expf(S[i0 + q4 * 4 + 1][j] - m) * inv;
    o.z = __expf(S[i0 + q4 * 4 + 2][j] - m) * inv;
    o.w = __expf(S[i0 + q4 * 4 + 3][j] - m) * inv;
    *(float4*)&osl[(size_t)j * 4096 + w * 64 + i0 + q4 * 4] = o;
  }
}

// ---------------- Stage C: col attention. block = bh*64 + h.
// S[i][j] = SCALE * sum_d cq[d,h,i]*ck[d,h,j]; softmax over i per j;
// write Csoft[bh][h][i][j]  (i = contraction index jj, j = w).
__global__ __launch_bounds__(256) void col_softmax(const float* __restrict__ p,
                                                   float* __restrict__ csoft) {
  const int blk = blockIdx.x;
  const int h   = blk & 63;
  const int bh  = blk >> 6;
  const float* pb = p + (size_t)(bh >> 3) * 1280 * 4096 + (size_t)(bh & 7) * 160 * 4096;
  __shared__ float cq[32][64];
  __shared__ float ck[32][64];
  __shared__ float S[64][65];
  __shared__ float mJ[64], sJ[64];
  const int t = threadIdx.x;
  {
    int f = t;
    int d = f >> 4, i4 = (f & 15) * 4;
    *(float4*)&cq[d][i4] = *(const float4*)&pb[(size_t)(64 + d) * 4096 + (size_t)h * 64 + i4];
    *(float4*)&ck[d][i4] = *(const float4*)&pb[(size_t)(96 + d) * 4096 + (size_t)h * 64 + i4];
    f = t + 256;
    d = f >> 4; i4 = (f & 15) * 4;
    *(float4*)&cq[d][i4] = *(const float4*)&pb[(size_t)(64 + d) * 4096 + (size_t)h * 64 + i4];
    *(float4*)&ck[d][i4] = *(const float4*)&pb[(size_t)(96 + d) * 4096 + (size_t)h * 64 + i4];
  }
  __syncthreads();
  const int ti = (t >> 4) * 4, tj = (t & 15) * 4;
  float a2[4][4];
#pragma unroll
  for (int q = 0; q < 4; q++)
#pragma unroll
    for (int r = 0; r < 4; r++) a2[q][r] = 0.f;
  for (int d = 0; d < 32; d++) {
    float4 av = *(const float4*)&cq[d][ti];
    float4 bv = *(const float4*)&ck[d][tj];
    const float* ap = &av.x;
    const float* bp = &bv.x;
#pragma unroll
    for (int q = 0; q < 4; q++)
#pragma unroll
      for (int r = 0; r < 4; r++)
        a2[q][r] = fmaf(ap[q], bp[r], a2[q][r]);
  }
#pragma unroll
  for (int q = 0; q < 4; q++)
#pragma unroll
    for (int r = 0; r < 4; r++)
      S[ti + q][tj + r] = a2[q][r] * SCALE;
  __syncthreads();
  if (t < 64) {
    const int j = t;
    float m = -1e30f;
    for (int i = 0; i < 64; i++) m = fmaxf(m, S[i][j]);
    float s = 0.f;
    for (int i = 0; i < 64; i++) s += __expf(S[i][j] - m);
    mJ[j] = m;
    sJ[j] = 1.f / s;
  }
  __syncthreads();
  float* osl = csoft + (size_t)bh * 64 * 4096 + (size_t)h * 4096;
  const int i = t >> 2, j0 = (t & 3) * 16;
#pragma unroll
  for (int q4 = 0; q4 < 4; q4++) {
    float4 o;
    o.x = __expf(S[i][j0 + q4 * 4 + 0] - mJ[j0 + q4 * 4 + 0]) * sJ[j0 + q4 * 4 + 0];
    o.y = __expf(S[i][j0 + q4 * 4 + 1] - mJ[j0 + q4 * 4 + 1]) * sJ[j0 + q4 * 4 + 1];
    o.z = __expf(S[i][j0 + q4 * 4 + 2] - mJ[j0 + q4 * 4 + 2]) * sJ[j0 + q4 * 4 + 2];
    o.w = __expf(S[i][j0 + q4 * 4 + 3] - mJ[j0 + q4 * 4 + 3]) * sJ[j0 + q4 * 4 + 3];
    *(float4*)&osl[(size_t)i * 64 + j0 + q4 * 4] = o;
  }
}

// ---------------- Stage E: transpose v per (bh,d): Vt[j][i] = v[i][j]
__global__ __launch_bounds__(256) void vtrans(const float* __restrict__ p,
                                              float* __restrict__ vt) {
  const int g  = blockIdx.x;          // bh*32 + d
  const int bh = g >> 5, d = g & 31;
  const int b  = bh >> 3, H = bh & 7;
  const float* src = p + ((size_t)b * 1280 + H * 160 + 128 + d) * 4096;
  float* dst = vt + (size_t)g * 4096;
  __shared__ float tile[64][65];
  const int t = threadIdx.x;
#pragma unroll
  for (int rep = 0; rep < 16; rep++) {
    int idx = rep * 256 + t;
    int i = idx >> 6, j = idx & 63;
    tile[i][j] = src[idx];
  }
  __syncthreads();
#pragma unroll
  for (int rep = 0; rep < 16; rep++) {
    int idx = rep * 256 + t;
    int j = idx >> 6, i = idx & 63;
    dst[idx] = tile[i][j];
  }
}

// ---------------- Stage D: apply. block = bh*16 + hq  (4 h-rows per block).
// out[d,h,w] = sum_j Csoft[h][j][w] * (sum_i Vt[d][j][i] * Rsoft[h][w][i]) + v[d,h,w]
__global__ __launch_bounds__(256, 1) void attn_apply(const float* __restrict__ p,
                                                     const float* __restrict__ rsoft,
                                                     const float* __restrict__ csoft,
                                                     const float* __restrict__ vt,
                                                     float* __restrict__ out) {
  __shared__ unsigned short rT[64][264];   // [i][p] bf16, row = 528B (16B aligned)
  __shared__ unsigned short vTL[32][68];   // [d][i] bf16, row = 136B (8B aligned)
  const int blk = blockIdx.x;
  const int bh  = blk >> 4;
  const int hq  = blk & 15;
  const int b   = bh >> 3, H = bh & 7;
  const int t   = threadIdx.x;
  const float* rsl = rsoft + (size_t)bh * 64 * 4096;
  const float* csl = csoft + (size_t)bh * 64 * 4096;
  const float* vts = vt + (size_t)bh * 32 * 4096;
  const float* pv  = p + ((size_t)b * 1280 + H * 160 + 128) * 4096;

  // stage rT[i][p] (p = h_l*64 + w) from Rsoft[bh][hq*4+h_l][w][i]
#pragma unroll
  for (int rep = 0; rep < 16; rep++) {
    int idx = rep * 256 + t;          // float4 index over 16384 values
    int h_l = idx >> 10;
    int rem = idx & 1023;
    int wl  = rem >> 4;
    int i4  = (rem & 15) * 4;
    float4 rv = *(const float4*)&rsl[(size_t)(hq * 4 + h_l) * 4096 + wl * 64 + i4];
    int pp = h_l * 64 + wl;
    rT[i4 + 0][pp] = f2bf(rv.x);
    rT[i4 + 1][pp] = f2bf(rv.y);
    rT[i4 + 2][pp] = f2bf(rv.z);
    rT[i4 + 3][pp] = f2bf(rv.w);
  }

  const int td = t & 7, pw = t >> 3;
  const int d0 = td * 4;
  const int p0 = pw * 8;
  const int h_l = p0 >> 6;
  const int w0  = p0 & 63;
  const int hrow = hq * 4 + h_l;

  float acc[4][8];
#pragma unroll
  for (int dd = 0; dd < 4; dd++)
#pragma unroll
    for (int q = 0; q < 8; q++) acc[dd][q] = 0.f;

  const int f0d = t >> 4,        f0i = (t & 15) * 4;
  const int f1d = (t >> 4) + 16, f1i = (t & 15) * 4;
  float4 pfa = *(const float4*)&vts[(size_t)f0d * 4096 + f0i];
  float4 pfb = *(const float4*)&vts[(size_t)f1d * 4096 + f1i];

  for (int j = 0; j < 64; j++) {
    *(uint2*)&vTL[f0d][f0i] = pack4(pfa);
    *(uint2*)&vTL[f1d][f1i] = pack4(pfb);
    __syncthreads();
    if (j < 63) {
      pfa = *(const float4*)&vts[(size_t)f0d * 4096 + (j + 1) * 64 + f0i];
      pfb = *(const float4*)&vts[(size_t)f1d * 4096 + (j + 1) * 64 + f1i];
    }
    float4 c0 = *(const float4*)&csl[(size_t)hrow * 4096 + j * 64 + w0];
    float4 c1 = *(const float4*)&csl[(size_t)hrow * 4096 + j * 64 + w0 + 4];

    float t4[4][8];
#pragma unroll
    for (int dd = 0; dd < 4; dd++)
#pragma unroll
      for (int q = 0; q < 8; q++) t4[dd][q] = 0.f;

#pragma unroll 4
    for (int i0 = 0; i0 < 64; i0 += 4) {
      float vv[4][4];
#pragma unroll
      for (int dd = 0; dd < 4; dd++) {
        uint2 u = *(const uint2*)&vTL[d0 + dd][i0];
        vv[dd][0] = bflo(u.x); vv[dd][1] = bfhi(u.x);
        vv[dd][2] = bflo(u.y); vv[dd][3] = bfhi(u.y);
      }
#pragma unroll
      for (int ii = 0; ii < 4; ii++) {
        uint4 u = *(const uint4*)&rT[i0 + ii][p0];
        float rr[8];
        rr[0] = bflo(u.x); rr[1] = bfhi(u.x);
        rr[2] = bflo(u.y); rr[3] = bfhi(u.y);
        rr[4] = bflo(u.z); rr[5] = bfhi(u.z);
        rr[6] = bflo(u.w); rr[7] = bfhi(u.w);
#pragma unroll
        for (int dd = 0; dd < 4; dd++)
#pragma unroll
          for (int q = 0; q < 8; q++)
            t4[dd][q] = fmaf(vv[dd][ii], rr[q], t4[dd][q]);
      }
    }
    float cr[8] = {c0.x, c0.y, c0.z, c0.w, c1.x, c1.y, c1.z, c1.w};
#pragma unroll
    for (int dd = 0; dd < 4; dd++)
#pragma unroll
      for (int q = 0; q < 8; q++)
        acc[dd][q] = fmaf(cr[q], t4[dd][q], acc[dd][q]);
    __syncthreads();
  }

  // epilogue: add v and store
#pragma unroll
  for (int dd = 0; dd < 4; dd++) {
    int d = d0 + dd;
    const float* vsrc = &pv[(size_t)d * 4096 + hrow * 64 + w0];
    float4 va = *(const float4*)&vsrc[0];
    float4 vb = *(const float4*)&vsrc[4];
    float4 oa, ob;
    oa.x = acc[dd][0] + va.x; oa.y = acc[dd][1] + va.y;
    oa.z = acc[dd][2] + va.z; oa.w = acc[dd][3] + va.w;
    ob.x = acc[dd][4] + vb.x; ob.y = acc[dd][5] + vb.y;
    ob.z = acc[dd][6] + vb.z; ob.w = acc[dd][7] + vb.w;
    float* od = out + ((size_t)(b * 256 + H * 32 + d)) * 4096 + hrow * 64 + w0;
    *(float4*)&od[0] = oa;
    *(float4*)&od[4] = ob;
  }
}

extern "C" void kernel_launch(void* const* d_in, const int* in_sizes, int n_in,
                              void* d_out, int out_size, void* d_ws, size_t ws_size,
                              hipStream_t stream) {
  const float* x = (const float*)d_in[0];
  const float* w = (const float*)d_in[1];
  float* out = (float*)d_out;
  float* ws  = (float*)d_ws;
  float* P  = ws;                 // 10,485,760 floats
  float* Rs = ws + 10485760;      //  4,194,304
  float* Cs = ws + 14680064;      //  4,194,304
  float* Vt = ws + 18874368;      //  2,097,152

  proj_gemm<<<dim3(32, 10, 2), 256, 0, stream>>>(x, w, P);
  row_softmax<<<1024, 256, 0, stream>>>(P, Rs);
  col_softmax<<<1024, 256, 0, stream>>>(P, Cs);
  vtrans<<<512, 256, 0, stream>>>(P, Vt);
  attn_apply<<<256, 256, 0, stream>>>(P, Rs, Cs, Vt, out);
}

// Round 3
// 173.037 us; speedup vs baseline: 2.9044x; 2.9044x over previous
//
#include <hip/hip_runtime.h>
#include <stdint.h>

// MatrixAttentionFunc: b=2, NH=8, KD=HD=32, D=256, 64x64 spatial.
// R3: R2 + fixed ws map (Cs was under-allocated 2x -> Vf/Cs clobber, absmax 16.6).
//
// ws layout (float units):
//   P    [2][1280][4096] fp32      @ 0          (10,485,760)
//   Rs   [bh][h][w][i]   fp32      @ 10485760   ( 4,194,304)
//   Cs   [bh][h][i][j]   bf16      @ 14680064   ( 2,097,152)   16*64*64*64 ushorts
//   Vf   [bh][j][fid][lane][8] bf16@ 16777216   ( 1,048,576)
//   Wbf  [1280][256]     bf16      @ 17825792   (   163,840)
//   Xt   [2][4096][256]  bf16      @ 17989632   ( 1,048,576)
// end 19,038,208 floats = 76.2 MB

#define SCALE 0.17677669529663687f
typedef unsigned short ushort_t;
typedef __attribute__((ext_vector_type(8))) short bf16x8;
typedef __attribute__((ext_vector_type(4))) float f32x4;
union U8 { uint4 u; bf16x8 v; };

__device__ __forceinline__ unsigned short f2bf(float f) {
  unsigned int b = __float_as_uint(f);
  b += 0x7fffu + ((b >> 16) & 1u);
  return (unsigned short)(b >> 16);
}
__device__ __forceinline__ float bflo(unsigned int u) { return __uint_as_float(u << 16); }
__device__ __forceinline__ unsigned int pk2(float a, float b) {
  return (unsigned int)f2bf(a) | ((unsigned int)f2bf(b) << 16);
}
__device__ __forceinline__ uint2 pack4(float4 f) {
  uint2 r; r.x = pk2(f.x, f.y); r.y = pk2(f.z, f.w); return r;
}
__device__ __forceinline__ bf16x8 packbf8(float4 a, float4 b) {
  U8 x; x.u.x = pk2(a.x, a.y); x.u.y = pk2(a.z, a.w);
  x.u.z = pk2(b.x, b.y); x.u.w = pk2(b.z, b.w); return x.v;
}
__device__ __forceinline__ f32x4 mfma16(bf16x8 a, bf16x8 b, f32x4 c) {
  return __builtin_amdgcn_mfma_f32_16x16x32_bf16(a, b, c, 0, 0, 0);
}

// ---------------- cvt_w: W fp32 -> bf16
__global__ __launch_bounds__(256) void cvt_w(const float* __restrict__ w,
                                             ushort_t* __restrict__ wbf) {
  const int idx = (blockIdx.x * 256 + threadIdx.x) * 8;
  float4 f0 = *(const float4*)&w[idx];
  float4 f1 = *(const float4*)&w[idx + 4];
  uint4 o; o.x = pk2(f0.x, f0.y); o.y = pk2(f0.z, f0.w);
  o.z = pk2(f1.x, f1.y); o.w = pk2(f1.z, f1.w);
  *(uint4*)&wbf[idx] = o;
}

// ---------------- xtrans: X[b][k][n] fp32 -> Xt[b][n][k] bf16
__global__ __launch_bounds__(256) void xtrans(const float* __restrict__ x,
                                              ushort_t* __restrict__ xt) {
  __shared__ float tile[128][33];
  const int b = blockIdx.z, k0 = blockIdx.y * 32, n0 = blockIdx.x * 128;
  const int t = threadIdx.x;
  const float* xb = x + (size_t)b * 256 * 4096;
#pragma unroll
  for (int rep = 0; rep < 4; rep++) {
    int idx = rep * 256 + t;              // 1024 float4 loads
    int kk = idx >> 5, nn4 = (idx & 31) * 4;
    float4 f = *(const float4*)&xb[(size_t)(k0 + kk) * 4096 + n0 + nn4];
    tile[nn4 + 0][kk] = f.x; tile[nn4 + 1][kk] = f.y;
    tile[nn4 + 2][kk] = f.z; tile[nn4 + 3][kk] = f.w;
  }
  __syncthreads();
  ushort_t* xo = xt + (size_t)b * 4096 * 256;
#pragma unroll
  for (int rep = 0; rep < 2; rep++) {
    int idx = rep * 256 + t;              // 512 uint4 stores
    int n = idx >> 2, k8 = (idx & 3) * 8;
    uint4 o;
    o.x = pk2(tile[n][k8 + 0], tile[n][k8 + 1]);
    o.y = pk2(tile[n][k8 + 2], tile[n][k8 + 3]);
    o.z = pk2(tile[n][k8 + 4], tile[n][k8 + 5]);
    o.w = pk2(tile[n][k8 + 6], tile[n][k8 + 7]);
    *(uint4*)&xo[(size_t)(n0 + n) * 256 + k0 + k8] = o;
  }
}

// ---------------- proj: P[b] = W(1280x256) @ X[b](256x4096), bf16 MFMA
__global__ __launch_bounds__(256, 2) void proj_mfma(const ushort_t* __restrict__ wbf,
                                                    const ushort_t* __restrict__ xt,
                                                    float* __restrict__ p) {
  __shared__ ushort_t Af[8 * 64 * 8];   // 8 m-frag blocks of 1KB
  __shared__ ushort_t Bf[8 * 64 * 8];
  const int b = blockIdx.z, m0 = blockIdx.y * 128, n0 = blockIdx.x * 128;
  const int t = threadIdx.x, wv = t >> 6, l = t & 63;
  const int row = l & 15, quad = l >> 4;
  const int wm = wv >> 1, wn = wv & 1;
  const ushort_t* xb = xt + (size_t)b * 4096 * 256;

  f32x4 acc[4][4];
#pragma unroll
  for (int i = 0; i < 4; i++)
#pragma unroll
    for (int j = 0; j < 4; j++) acc[i][j] = (f32x4){0.f, 0.f, 0.f, 0.f};

  const size_t aoff0 = (size_t)(m0 + (2 * wv + 0) * 16 + row) * 256 + quad * 8;
  const size_t aoff1 = (size_t)(m0 + (2 * wv + 1) * 16 + row) * 256 + quad * 8;
  const size_t boff0 = (size_t)(n0 + (2 * wv + 0) * 16 + row) * 256 + quad * 8;
  const size_t boff1 = (size_t)(n0 + (2 * wv + 1) * 16 + row) * 256 + quad * 8;

  for (int k0 = 0; k0 < 256; k0 += 32) {
    uint4 a0 = *(const uint4*)&wbf[aoff0 + k0];
    uint4 a1 = *(const uint4*)&wbf[aoff1 + k0];
    uint4 b0 = *(const uint4*)&xb[boff0 + k0];
    uint4 b1 = *(const uint4*)&xb[boff1 + k0];
    __syncthreads();                       // previous iter's reads done
    *(uint4*)&Af[((2 * wv + 0) * 64 + l) * 8] = a0;
    *(uint4*)&Af[((2 * wv + 1) * 64 + l) * 8] = a1;
    *(uint4*)&Bf[((2 * wv + 0) * 64 + l) * 8] = b0;
    *(uint4*)&Bf[((2 * wv + 1) * 64 + l) * 8] = b1;
    __syncthreads();
    bf16x8 af[4], bfr[4];
#pragma unroll
    for (int mf = 0; mf < 4; mf++) af[mf] = *(bf16x8*)&Af[((wm * 4 + mf) * 64 + l) * 8];
#pragma unroll
    for (int nf = 0; nf < 4; nf++) bfr[nf] = *(bf16x8*)&Bf[((wn * 4 + nf) * 64 + l) * 8];
#pragma unroll
    for (int mf = 0; mf < 4; mf++)
#pragma unroll
      for (int nf = 0; nf < 4; nf++)
        acc[mf][nf] = mfma16(af[mf], bfr[nf], acc[mf][nf]);
  }
  float* pb = p + (size_t)b * 1280 * 4096;
#pragma unroll
  for (int mf = 0; mf < 4; mf++)
#pragma unroll
    for (int nf = 0; nf < 4; nf++)
#pragma unroll
      for (int reg = 0; reg < 4; reg++) {
        int m = m0 + wm * 64 + mf * 16 + quad * 4 + reg;
        int n = n0 + wn * 64 + nf * 16 + row;
        pb[(size_t)m * 4096 + n] = acc[mf][nf][reg];
      }
}

// ---------------- row attention softmax (fp32 out)
__global__ __launch_bounds__(256) void row_softmax(const float* __restrict__ p,
                                                   float* __restrict__ rsoft) {
  const int blk = blockIdx.x;
  const int w = blk & 63;
  const int bh = blk >> 6;
  const float* pb = p + (size_t)(bh >> 3) * 1280 * 4096 + (size_t)(bh & 7) * 160 * 4096;
  __shared__ float rq[32][64];
  __shared__ float rk[32][64];
  __shared__ float S[64][65];
  __shared__ float mJ[64], sJ[64];
  const int t = threadIdx.x;
#pragma unroll
  for (int rep = 0; rep < 8; rep++) {
    int idx = rep * 256 + t;
    int d = idx >> 6, i = idx & 63;
    rq[d][i] = pb[(size_t)d * 4096 + i * 64 + w];
    rk[d][i] = pb[(size_t)(32 + d) * 4096 + i * 64 + w];
  }
  __syncthreads();
  const int ti = (t >> 4) * 4, tj = (t & 15) * 4;
  float a2[4][4];
#pragma unroll
  for (int q = 0; q < 4; q++)
#pragma unroll
    for (int r = 0; r < 4; r++) a2[q][r] = 0.f;
  for (int d = 0; d < 32; d++) {
    float4 av = *(const float4*)&rq[d][ti];
    float4 bv = *(const float4*)&rk[d][tj];
    const float* ap = &av.x;
    const float* bp = &bv.x;
#pragma unroll
    for (int q = 0; q < 4; q++)
#pragma unroll
      for (int r = 0; r < 4; r++)
        a2[q][r] = fmaf(ap[q], bp[r], a2[q][r]);
  }
#pragma unroll
  for (int q = 0; q < 4; q++)
#pragma unroll
    for (int r = 0; r < 4; r++)
      S[ti + q][tj + r] = a2[q][r] * SCALE;
  __syncthreads();
  if (t < 64) {
    const int j = t;
    float m = -1e30f;
    for (int i = 0; i < 64; i++) m = fmaxf(m, S[i][j]);
    float s = 0.f;
    for (int i = 0; i < 64; i++) s += __expf(S[i][j] - m);
    mJ[j] = m;
    sJ[j] = 1.f / s;
  }
  __syncthreads();
  float* osl = rsoft + (size_t)bh * 64 * 4096;
  const int j = t >> 2, i0 = (t & 3) * 16;
  const float m = mJ[j], inv = sJ[j];
#pragma unroll
  for (int q4 = 0; q4 < 4; q4++) {
    float4 o;
    o.x = __expf(S[i0 + q4 * 4 + 0][j] - m) * inv;
    o.y = __expf(S[i0 + q4 * 4 + 1][j] - m) * inv;
    o.z = __expf(S[i0 + q4 * 4 + 2][j] - m) * inv;
    o.w = __expf(S[i0 + q4 * 4 + 3][j] - m) * inv;
    *(float4*)&osl[(size_t)j * 4096 + w * 64 + i0 + q4 * 4] = o;
  }
}

// ---------------- col attention softmax (bf16 out)
__global__ __launch_bounds__(256) void col_softmax(const float* __restrict__ p,
                                                   ushort_t* __restrict__ csoft) {
  const int blk = blockIdx.x;
  const int h = blk & 63;
  const int bh = blk >> 6;
  const float* pb = p + (size_t)(bh >> 3) * 1280 * 4096 + (size_t)(bh & 7) * 160 * 4096;
  __shared__ float cq[32][64];
  __shared__ float ck[32][64];
  __shared__ float S[64][65];
  __shared__ float mJ[64], sJ[64];
  const int t = threadIdx.x;
  {
    int f = t;
    int d = f >> 4, i4 = (f & 15) * 4;
    *(float4*)&cq[d][i4] = *(const float4*)&pb[(size_t)(64 + d) * 4096 + (size_t)h * 64 + i4];
    *(float4*)&ck[d][i4] = *(const float4*)&pb[(size_t)(96 + d) * 4096 + (size_t)h * 64 + i4];
    f = t + 256;
    d = f >> 4; i4 = (f & 15) * 4;
    *(float4*)&cq[d][i4] = *(const float4*)&pb[(size_t)(64 + d) * 4096 + (size_t)h * 64 + i4];
    *(float4*)&ck[d][i4] = *(const float4*)&pb[(size_t)(96 + d) * 4096 + (size_t)h * 64 + i4];
  }
  __syncthreads();
  const int ti = (t >> 4) * 4, tj = (t & 15) * 4;
  float a2[4][4];
#pragma unroll
  for (int q = 0; q < 4; q++)
#pragma unroll
    for (int r = 0; r < 4; r++) a2[q][r] = 0.f;
  for (int d = 0; d < 32; d++) {
    float4 av = *(const float4*)&cq[d][ti];
    float4 bv = *(const float4*)&ck[d][tj];
    const float* ap = &av.x;
    const float* bp = &bv.x;
#pragma unroll
    for (int q = 0; q < 4; q++)
#pragma unroll
      for (int r = 0; r < 4; r++)
        a2[q][r] = fmaf(ap[q], bp[r], a2[q][r]);
  }
#pragma unroll
  for (int q = 0; q < 4; q++)
#pragma unroll
    for (int r = 0; r < 4; r++)
      S[ti + q][tj + r] = a2[q][r] * SCALE;
  __syncthreads();
  if (t < 64) {
    const int j = t;
    float m = -1e30f;
    for (int i = 0; i < 64; i++) m = fmaxf(m, S[i][j]);
    float s = 0.f;
    for (int i = 0; i < 64; i++) s += __expf(S[i][j] - m);
    mJ[j] = m;
    sJ[j] = 1.f / s;
  }
  __syncthreads();
  ushort_t* osl = csoft + (size_t)bh * 64 * 4096 + (size_t)h * 4096;
  const int i = t >> 2, j0 = (t & 3) * 16;
#pragma unroll
  for (int q4 = 0; q4 < 4; q4++) {
    float4 o;
    o.x = __expf(S[i][j0 + q4 * 4 + 0] - mJ[j0 + q4 * 4 + 0]) * sJ[j0 + q4 * 4 + 0];
    o.y = __expf(S[i][j0 + q4 * 4 + 1] - mJ[j0 + q4 * 4 + 1]) * sJ[j0 + q4 * 4 + 1];
    o.z = __expf(S[i][j0 + q4 * 4 + 2] - mJ[j0 + q4 * 4 + 2]) * sJ[j0 + q4 * 4 + 2];
    o.w = __expf(S[i][j0 + q4 * 4 + 3] - mJ[j0 + q4 * 4 + 3]) * sJ[j0 + q4 * 4 + 3];
    *(uint2*)&osl[(size_t)i * 64 + j0 + q4 * 4] = pack4(o);
  }
}

// ---------------- vtrans: v[d,i,j] -> Vf[bh][j][fid][lane][8e] bf16 (MFMA A-frag order)
// fid = kc*2+mf; d = mf*16 + (lane&15); i = kc*32 + (lane>>4)*8 + e
__global__ __launch_bounds__(256) void vtrans(const float* __restrict__ p,
                                              ushort_t* __restrict__ vf) {
  __shared__ float tile[8][64][33];   // [jl][i][d]
  const int jc = blockIdx.x;          // 8 chunks of 8 j
  const int bh = blockIdx.y;
  const int b = bh >> 3, H = bh & 7;
  const int j0 = jc * 8;
  const float* pvb = p + ((size_t)b * 1280 + H * 160 + 128) * 4096;
  const int t = threadIdx.x;
#pragma unroll
  for (int rep = 0; rep < 8; rep++) {
    int idx = rep * 256 + t;
    int d = idx >> 6, i = idx & 63;
    float4 f0 = *(const float4*)&pvb[(size_t)d * 4096 + i * 64 + j0];
    float4 f1 = *(const float4*)&pvb[(size_t)d * 4096 + i * 64 + j0 + 4];
    tile[0][i][d] = f0.x; tile[1][i][d] = f0.y;
    tile[2][i][d] = f0.z; tile[3][i][d] = f0.w;
    tile[4][i][d] = f1.x; tile[5][i][d] = f1.y;
    tile[6][i][d] = f1.z; tile[7][i][d] = f1.w;
  }
  __syncthreads();
  ushort_t* vo = vf + (size_t)bh * 131072;
  const int fid = t >> 6, l = t & 63;
  const int d = (fid & 1) * 16 + (l & 15);
  const int i0 = (fid >> 1) * 32 + (l >> 4) * 8;
#pragma unroll
  for (int rep = 0; rep < 8; rep++) {
    int jl = rep;
    uint4 o;
    o.x = pk2(tile[jl][i0 + 0][d], tile[jl][i0 + 1][d]);
    o.y = pk2(tile[jl][i0 + 2][d], tile[jl][i0 + 3][d]);
    o.z = pk2(tile[jl][i0 + 4][d], tile[jl][i0 + 5][d]);
    o.w = pk2(tile[jl][i0 + 6][d], tile[jl][i0 + 7][d]);
    *(uint4*)&vo[(size_t)(((j0 + jl) * 4 + fid) * 64 + l) * 8] = o;
  }
}

// ---------------- apply: out[d,p] = sum_j c[j,p] * (sum_i v[d,i,j] r[i,p]) + v[d,p]
__global__ __launch_bounds__(256) void attn_apply_mfma(const float* __restrict__ p,
                                                       const float* __restrict__ rs,
                                                       const ushort_t* __restrict__ cs,
                                                       const ushort_t* __restrict__ vf,
                                                       float* __restrict__ out) {
  const int blk = blockIdx.x;           // bh*32 + ct
  const int bh = blk >> 5, ct = blk & 31;
  const int b = bh >> 3, H = bh & 7;
  const int t = threadIdx.x, wv = t >> 6, l = t & 63;
  const int row = l & 15, quad = l >> 4;
  const int p0 = ct * 128 + wv * 32;
  const int h = p0 >> 6, w0 = p0 & 63;  // w0 in {0,32}
  const float* rsl = rs + (size_t)bh * 262144;
  const ushort_t* csl = cs + (size_t)bh * 262144 + h * 4096 + w0;
  const uint4* vq = (const uint4*)(vf + (size_t)bh * 131072);

  // B-fragments (r), loaded once: rf[nf][kc]
  bf16x8 rf[2][2];
#pragma unroll
  for (int nf = 0; nf < 2; nf++) {
    const int wcol = w0 + nf * 16 + row;
    const float* rp = &rsl[(size_t)(h * 64 + wcol) * 64 + quad * 8];
#pragma unroll
    for (int kc = 0; kc < 2; kc++) {
      float4 f0 = *(const float4*)&rp[kc * 32];
      float4 f1 = *(const float4*)&rp[kc * 32 + 4];
      rf[nf][kc] = packbf8(f0, f1);
    }
  }

  f32x4 acc[2][2];
#pragma unroll
  for (int i = 0; i < 2; i++)
#pragma unroll
    for (int j = 0; j < 2; j++) acc[i][j] = (f32x4){0.f, 0.f, 0.f, 0.f};

  uint4 av[4];
#pragma unroll
  for (int fid = 0; fid < 4; fid++) av[fid] = vq[fid * 64 + l];

  for (int j = 0; j < 64; j++) {
    uint4 an[4];
    if (j < 63) {
#pragma unroll
      for (int fid = 0; fid < 4; fid++) an[fid] = vq[((j + 1) * 4 + fid) * 64 + l];
    }
    float c0 = bflo((unsigned int)csl[j * 64 + row]);
    float c1 = bflo((unsigned int)csl[j * 64 + 16 + row]);
#pragma unroll
    for (int mf = 0; mf < 2; mf++) {
      U8 ua0, ua1; ua0.u = av[mf]; ua1.u = av[2 + mf];
#pragma unroll
      for (int nf = 0; nf < 2; nf++) {
        f32x4 tt = (f32x4){0.f, 0.f, 0.f, 0.f};
        tt = mfma16(ua0.v, rf[nf][0], tt);
        tt = mfma16(ua1.v, rf[nf][1], tt);
        float cv = nf ? c1 : c0;
        acc[mf][nf] += tt * cv;
      }
    }
#pragma unroll
    for (int fid = 0; fid < 4; fid++) av[fid] = an[fid];
  }

  const float* pv = p + ((size_t)b * 1280 + H * 160 + 128) * 4096 + h * 64;
  float* ob = out + ((size_t)b * 256 + H * 32) * 4096 + h * 64;
#pragma unroll
  for (int mf = 0; mf < 2; mf++)
#pragma unroll
    for (int nf = 0; nf < 2; nf++)
#pragma unroll
      for (int reg = 0; reg < 4; reg++) {
        int d = mf * 16 + quad * 4 + reg;
        int wc = w0 + nf * 16 + row;
        ob[(size_t)d * 4096 + wc] = acc[mf][nf][reg] + pv[(size_t)d * 4096 + wc];
      }
}

extern "C" void kernel_launch(void* const* d_in, const int* in_sizes, int n_in,
                              void* d_out, int out_size, void* d_ws, size_t ws_size,
                              hipStream_t stream) {
  const float* x = (const float*)d_in[0];
  const float* w = (const float*)d_in[1];
  float* out = (float*)d_out;
  float* ws = (float*)d_ws;
  float* P = ws;                                    // 10,485,760 f
  float* Rs = ws + 10485760;                        //  4,194,304 f
  ushort_t* Cs = (ushort_t*)(ws + 14680064);        //  2,097,152 f (bf16, 4,194,304 vals)
  ushort_t* Vf = (ushort_t*)(ws + 16777216);        //  1,048,576 f (bf16)
  ushort_t* Wbf = (ushort_t*)(ws + 17825792);       //    163,840 f (bf16)
  ushort_t* Xt = (ushort_t*)(ws + 17989632);        //  1,048,576 f (bf16)

  cvt_w<<<160, 256, 0, stream>>>(w, Wbf);
  xtrans<<<dim3(32, 8, 2), 256, 0, stream>>>(x, Xt);
  proj_mfma<<<dim3(32, 10, 2), 256, 0, stream>>>(Wbf, Xt, P);
  row_softmax<<<1024, 256, 0, stream>>>(P, Rs);
  col_softmax<<<1024, 256, 0, stream>>>(P, Cs);
  vtrans<<<dim3(8, 16), 256, 0, stream>>>(P, Vf);
  attn_apply_mfma<<<512, 256, 0, stream>>>(P, Rs, Cs, Vf, out);
}

// Round 4
// 157.918 us; speedup vs baseline: 3.1825x; 1.0957x over previous
//
#include <hip/hip_runtime.h>
#include <stdint.h>

// MatrixAttentionFunc: b=2, NH=8, KD=HD=32, D=256, 64x64 spatial.
// R4: LDS-staged apply (global_load_lds dbuf, j-split), coalesced score path.
//
// ws layout (float units), total 19,038,208 fu = 76.15 MB (same as R3):
//   P    [2][1280][4096] fp32      @ 0          (10,485,760)
//   Rs   [bh][j][w][i]   bf16      @ 10485760   ( 2,097,152)
//   Cs   [bh][h][a][b]   bf16      @ 12582912   ( 2,097,152)
//   Vf   [bh][j][fid][lane][8] bf16@ 14680064   ( 1,048,576)
//   TQ0  [bh][row][32d]  bf16      @ 15728640   ( 1,048,576)  (Qr then Qc)
//   TQ1  [bh][row][32d]  bf16      @ 16777216   ( 1,048,576)  (Kr then Kc)
//   Wbf  [1280][256]     bf16      @ 17825792   (   163,840)
//   Xt   [2][4096][256]  bf16      @ 17989632   ( 1,048,576)
//   Pp1  fp32 (2,097,152 fu)       @ 15728640   aliases TQ0+TQ1 (dead by then)

#define SCALE 0.17677669529663687f
typedef unsigned short ushort_t;
typedef __attribute__((ext_vector_type(8))) short bf16x8;
typedef __attribute__((ext_vector_type(4))) float f32x4;
union U8 { uint4 u; bf16x8 v; };

__device__ __forceinline__ unsigned short f2bf(float f) {
  unsigned int b = __float_as_uint(f);
  b += 0x7fffu + ((b >> 16) & 1u);
  return (unsigned short)(b >> 16);
}
__device__ __forceinline__ float bflo(unsigned int u) { return __uint_as_float(u << 16); }
__device__ __forceinline__ float bfhi(unsigned int u) { return __uint_as_float(u & 0xffff0000u); }
__device__ __forceinline__ unsigned int pk2(float a, float b) {
  return (unsigned int)f2bf(a) | ((unsigned int)f2bf(b) << 16);
}
__device__ __forceinline__ f32x4 mfma16(bf16x8 a, bf16x8 b, f32x4 c) {
  return __builtin_amdgcn_mfma_f32_16x16x32_bf16(a, b, c, 0, 0, 0);
}
__device__ __forceinline__ void gld16(const void* g, void* l) {
  __builtin_amdgcn_global_load_lds(
      (const __attribute__((address_space(1))) unsigned int*)g,
      (__attribute__((address_space(3))) unsigned int*)l, 16, 0, 0);
}

// ---------------- cvt_w: W fp32 -> bf16
__global__ __launch_bounds__(256) void cvt_w(const float* __restrict__ w,
                                             ushort_t* __restrict__ wbf) {
  const int idx = (blockIdx.x * 256 + threadIdx.x) * 8;
  float4 f0 = *(const float4*)&w[idx];
  float4 f1 = *(const float4*)&w[idx + 4];
  uint4 o; o.x = pk2(f0.x, f0.y); o.y = pk2(f0.z, f0.w);
  o.z = pk2(f1.x, f1.y); o.w = pk2(f1.z, f1.w);
  *(uint4*)&wbf[idx] = o;
}

// ---------------- xtrans: X[b][k][n] fp32 -> Xt[b][n][k] bf16
__global__ __launch_bounds__(256) void xtrans(const float* __restrict__ x,
                                              ushort_t* __restrict__ xt) {
  __shared__ float tile[128][33];
  const int b = blockIdx.z, k0 = blockIdx.y * 32, n0 = blockIdx.x * 128;
  const int t = threadIdx.x;
  const float* xb = x + (size_t)b * 256 * 4096;
#pragma unroll
  for (int rep = 0; rep < 4; rep++) {
    int idx = rep * 256 + t;
    int kk = idx >> 5, nn4 = (idx & 31) * 4;
    float4 f = *(const float4*)&xb[(size_t)(k0 + kk) * 4096 + n0 + nn4];
    tile[nn4 + 0][kk] = f.x; tile[nn4 + 1][kk] = f.y;
    tile[nn4 + 2][kk] = f.z; tile[nn4 + 3][kk] = f.w;
  }
  __syncthreads();
  ushort_t* xo = xt + (size_t)b * 4096 * 256;
#pragma unroll
  for (int rep = 0; rep < 2; rep++) {
    int idx = rep * 256 + t;
    int n = idx >> 2, k8 = (idx & 3) * 8;
    uint4 o;
    o.x = pk2(tile[n][k8 + 0], tile[n][k8 + 1]);
    o.y = pk2(tile[n][k8 + 2], tile[n][k8 + 3]);
    o.z = pk2(tile[n][k8 + 4], tile[n][k8 + 5]);
    o.w = pk2(tile[n][k8 + 6], tile[n][k8 + 7]);
    *(uint4*)&xo[(size_t)(n0 + n) * 256 + k0 + k8] = o;
  }
}

// ---------------- proj: P[b] = W(1280x256) @ X[b](256x4096), bf16 MFMA (as R3)
__global__ __launch_bounds__(256, 2) void proj_mfma(const ushort_t* __restrict__ wbf,
                                                    const ushort_t* __restrict__ xt,
                                                    float* __restrict__ p) {
  __shared__ ushort_t Af[8 * 64 * 8];
  __shared__ ushort_t Bf[8 * 64 * 8];
  const int b = blockIdx.z, m0 = blockIdx.y * 128, n0 = blockIdx.x * 128;
  const int t = threadIdx.x, wv = t >> 6, l = t & 63;
  const int row = l & 15, quad = l >> 4;
  const int wm = wv >> 1, wn = wv & 1;
  const ushort_t* xb = xt + (size_t)b * 4096 * 256;

  f32x4 acc[4][4];
#pragma unroll
  for (int i = 0; i < 4; i++)
#pragma unroll
    for (int j = 0; j < 4; j++) acc[i][j] = (f32x4){0.f, 0.f, 0.f, 0.f};

  const size_t aoff0 = (size_t)(m0 + (2 * wv + 0) * 16 + row) * 256 + quad * 8;
  const size_t aoff1 = (size_t)(m0 + (2 * wv + 1) * 16 + row) * 256 + quad * 8;
  const size_t boff0 = (size_t)(n0 + (2 * wv + 0) * 16 + row) * 256 + quad * 8;
  const size_t boff1 = (size_t)(n0 + (2 * wv + 1) * 16 + row) * 256 + quad * 8;

  for (int k0 = 0; k0 < 256; k0 += 32) {
    uint4 a0 = *(const uint4*)&wbf[aoff0 + k0];
    uint4 a1 = *(const uint4*)&wbf[aoff1 + k0];
    uint4 b0 = *(const uint4*)&xb[boff0 + k0];
    uint4 b1 = *(const uint4*)&xb[boff1 + k0];
    __syncthreads();
    *(uint4*)&Af[((2 * wv + 0) * 64 + l) * 8] = a0;
    *(uint4*)&Af[((2 * wv + 1) * 64 + l) * 8] = a1;
    *(uint4*)&Bf[((2 * wv + 0) * 64 + l) * 8] = b0;
    *(uint4*)&Bf[((2 * wv + 1) * 64 + l) * 8] = b1;
    __syncthreads();
    bf16x8 af[4], bfr[4];
#pragma unroll
    for (int mf = 0; mf < 4; mf++) af[mf] = *(bf16x8*)&Af[((wm * 4 + mf) * 64 + l) * 8];
#pragma unroll
    for (int nf = 0; nf < 4; nf++) bfr[nf] = *(bf16x8*)&Bf[((wn * 4 + nf) * 64 + l) * 8];
#pragma unroll
    for (int mf = 0; mf < 4; mf++)
#pragma unroll
      for (int nf = 0; nf < 4; nf++)
        acc[mf][nf] = mfma16(af[mf], bfr[nf], acc[mf][nf]);
  }
  float* pb = p + (size_t)b * 1280 * 4096;
#pragma unroll
  for (int mf = 0; mf < 4; mf++)
#pragma unroll
    for (int nf = 0; nf < 4; nf++)
#pragma unroll
      for (int reg = 0; reg < 4; reg++) {
        int m = m0 + wm * 64 + mf * 16 + quad * 4 + reg;
        int n = n0 + wn * 64 + nf * 16 + row;
        pb[(size_t)m * 4096 + n] = acc[mf][nf][reg];
      }
}

// ---------------- qk_trans: P q/k sections -> [bh][row][32d] bf16.
// mode 0 (row-attn): sections rq/rk, out row = (p&63)*64 + (p>>6)  ([w][i][d])
// mode 1 (col-attn): sections cq/ck, out row = p                   ([h][i][d])
// Reads coalesced (lanes = consecutive p); writes 64B rows.
__global__ __launch_bounds__(256) void qk_trans(const float* __restrict__ P,
                                                ushort_t* __restrict__ dq,
                                                ushort_t* __restrict__ dk,
                                                int mode) {
  const int chunk = blockIdx.x & 15, bh = blockIdx.x >> 4;
  const int qk = blockIdx.y;
  const int b = bh >> 3, H = bh & 7;
  const float* src = P + ((size_t)b * 1280 + H * 160 + mode * 64 + qk * 32) * 4096;
  ushort_t* dst = (qk ? dk : dq) + (size_t)bh * 131072;
  const int t = threadIdx.x;
  const int p = chunk * 256 + t;
  const int orow = mode ? p : ((p & 63) * 64 + (p >> 6));
  float v[32];
#pragma unroll
  for (int d = 0; d < 32; d++) v[d] = src[(size_t)d * 4096 + p];
  ushort_t* drow = &dst[(size_t)orow * 32];
#pragma unroll
  for (int c = 0; c < 4; c++) {
    uint4 o;
    o.x = pk2(v[c * 8 + 0], v[c * 8 + 1]);
    o.y = pk2(v[c * 8 + 2], v[c * 8 + 3]);
    o.z = pk2(v[c * 8 + 4], v[c * 8 + 5]);
    o.w = pk2(v[c * 8 + 6], v[c * 8 + 7]);
    *(uint4*)&drow[c * 8] = o;
  }
}

// ---------------- row softmax v2: block=(bh,w), reads Qr/Kr [w][i][d] bf16.
// S[i][j] = SCALE * sum_d q[i][d] k[j][d]; softmax over i per j; Rs[j][w][i] bf16.
__global__ __launch_bounds__(256) void row_softmax_v2(const ushort_t* __restrict__ qr,
                                                      const ushort_t* __restrict__ kr,
                                                      ushort_t* __restrict__ rsoft) {
  const int blk = blockIdx.x;
  const int w = blk & 63, bh = blk >> 6;
  __shared__ float rqf[32][68];
  __shared__ float rkf[32][68];
  __shared__ float S[64][65];
  __shared__ float mJ[64], sJ[64];
  const int t = threadIdx.x;
  const ushort_t* qs = qr + ((size_t)bh * 64 + w) * 2048;
  const ushort_t* ks = kr + ((size_t)bh * 64 + w) * 2048;
  {
    uint4 uq = *(const uint4*)&qs[t * 8];
    uint4 uk = *(const uint4*)&ks[t * 8];
    int i = t >> 2, d0 = (t & 3) * 8;
    rqf[d0 + 0][i] = bflo(uq.x); rqf[d0 + 1][i] = bfhi(uq.x);
    rqf[d0 + 2][i] = bflo(uq.y); rqf[d0 + 3][i] = bfhi(uq.y);
    rqf[d0 + 4][i] = bflo(uq.z); rqf[d0 + 5][i] = bfhi(uq.z);
    rqf[d0 + 6][i] = bflo(uq.w); rqf[d0 + 7][i] = bfhi(uq.w);
    rkf[d0 + 0][i] = bflo(uk.x); rkf[d0 + 1][i] = bfhi(uk.x);
    rkf[d0 + 2][i] = bflo(uk.y); rkf[d0 + 3][i] = bfhi(uk.y);
    rkf[d0 + 4][i] = bflo(uk.z); rkf[d0 + 5][i] = bfhi(uk.z);
    rkf[d0 + 6][i] = bflo(uk.w); rkf[d0 + 7][i] = bfhi(uk.w);
  }
  __syncthreads();
  const int ti = (t >> 4) * 4, tj = (t & 15) * 4;
  float a2[4][4];
#pragma unroll
  for (int q = 0; q < 4; q++)
#pragma unroll
    for (int r = 0; r < 4; r++) a2[q][r] = 0.f;
  for (int d = 0; d < 32; d++) {
    float4 av = *(const float4*)&rqf[d][ti];
    float4 bv = *(const float4*)&rkf[d][tj];
    const float* ap = &av.x;
    const float* bp = &bv.x;
#pragma unroll
    for (int q = 0; q < 4; q++)
#pragma unroll
      for (int r = 0; r < 4; r++)
        a2[q][r] = fmaf(ap[q], bp[r], a2[q][r]);
  }
#pragma unroll
  for (int q = 0; q < 4; q++)
#pragma unroll
    for (int r = 0; r < 4; r++)
      S[ti + q][tj + r] = a2[q][r] * SCALE;
  __syncthreads();
  if (t < 64) {
    const int j = t;
    float m = -1e30f;
    for (int i = 0; i < 64; i++) m = fmaxf(m, S[i][j]);
    float s = 0.f;
    for (int i = 0; i < 64; i++) s += __expf(S[i][j] - m);
    mJ[j] = m;
    sJ[j] = 1.f / s;
  }
  __syncthreads();
  ushort_t* osl = rsoft + (size_t)bh * 262144;
  const int j = t >> 2, i0 = (t & 3) * 16;
  const float m = mJ[j], inv = sJ[j];
#pragma unroll
  for (int q4 = 0; q4 < 2; q4++) {
    float e[8];
#pragma unroll
    for (int c = 0; c < 8; c++) e[c] = __expf(S[i0 + q4 * 8 + c][j] - m) * inv;
    uint4 o;
    o.x = pk2(e[0], e[1]); o.y = pk2(e[2], e[3]);
    o.z = pk2(e[4], e[5]); o.w = pk2(e[6], e[7]);
    *(uint4*)&osl[((size_t)j * 64 + w) * 64 + i0 + q4 * 8] = o;
  }
}

// ---------------- col softmax v2: block=(bh,h), reads Qc/Kc [h][i][d] bf16.
// S[a][b] = SCALE * sum_d q[a][d] k[b][d]; softmax over a per b; Cs[h][a][b] bf16.
__global__ __launch_bounds__(256) void col_softmax_v2(const ushort_t* __restrict__ qc,
                                                      const ushort_t* __restrict__ kc,
                                                      ushort_t* __restrict__ csoft) {
  const int blk = blockIdx.x;
  const int h = blk & 63, bh = blk >> 6;
  __shared__ float rqf[32][68];
  __shared__ float rkf[32][68];
  __shared__ float S[64][65];
  __shared__ float mJ[64], sJ[64];
  const int t = threadIdx.x;
  const ushort_t* qs = qc + ((size_t)bh * 64 + h) * 2048;
  const ushort_t* ks = kc + ((size_t)bh * 64 + h) * 2048;
  {
    uint4 uq = *(const uint4*)&qs[t * 8];
    uint4 uk = *(const uint4*)&ks[t * 8];
    int i = t >> 2, d0 = (t & 3) * 8;
    rqf[d0 + 0][i] = bflo(uq.x); rqf[d0 + 1][i] = bfhi(uq.x);
    rqf[d0 + 2][i] = bflo(uq.y); rqf[d0 + 3][i] = bfhi(uq.y);
    rqf[d0 + 4][i] = bflo(uq.z); rqf[d0 + 5][i] = bfhi(uq.z);
    rqf[d0 + 6][i] = bflo(uq.w); rqf[d0 + 7][i] = bfhi(uq.w);
    rkf[d0 + 0][i] = bflo(uk.x); rkf[d0 + 1][i] = bfhi(uk.x);
    rkf[d0 + 2][i] = bflo(uk.y); rkf[d0 + 3][i] = bfhi(uk.y);
    rkf[d0 + 4][i] = bflo(uk.z); rkf[d0 + 5][i] = bfhi(uk.z);
    rkf[d0 + 6][i] = bflo(uk.w); rkf[d0 + 7][i] = bfhi(uk.w);
  }
  __syncthreads();
  const int ti = (t >> 4) * 4, tj = (t & 15) * 4;
  float a2[4][4];
#pragma unroll
  for (int q = 0; q < 4; q++)
#pragma unroll
    for (int r = 0; r < 4; r++) a2[q][r] = 0.f;
  for (int d = 0; d < 32; d++) {
    float4 av = *(const float4*)&rqf[d][ti];
    float4 bv = *(const float4*)&rkf[d][tj];
    const float* ap = &av.x;
    const float* bp = &bv.x;
#pragma unroll
    for (int q = 0; q < 4; q++)
#pragma unroll
      for (int r = 0; r < 4; r++)
        a2[q][r] = fmaf(ap[q], bp[r], a2[q][r]);
  }
#pragma unroll
  for (int q = 0; q < 4; q++)
#pragma unroll
    for (int r = 0; r < 4; r++)
      S[ti + q][tj + r] = a2[q][r] * SCALE;
  __syncthreads();
  if (t < 64) {
    const int j = t;
    float m = -1e30f;
    for (int i = 0; i < 64; i++) m = fmaxf(m, S[i][j]);
    float s = 0.f;
    for (int i = 0; i < 64; i++) s += __expf(S[i][j] - m);
    mJ[j] = m;
    sJ[j] = 1.f / s;
  }
  __syncthreads();
  ushort_t* osl = csoft + (size_t)bh * 262144 + (size_t)h * 4096;
  const int a = t >> 2, b0 = (t & 3) * 16;
#pragma unroll
  for (int q4 = 0; q4 < 2; q4++) {
    float e[8];
#pragma unroll
    for (int c = 0; c < 8; c++) {
      int b = b0 + q4 * 8 + c;
      e[c] = __expf(S[a][b] - mJ[b]) * sJ[b];
    }
    uint4 o;
    o.x = pk2(e[0], e[1]); o.y = pk2(e[2], e[3]);
    o.z = pk2(e[4], e[5]); o.w = pk2(e[6], e[7]);
    *(uint4*)&osl[(size_t)a * 64 + b0 + q4 * 8] = o;
  }
}

// ---------------- vtrans: v[d,i,j] -> Vf[bh][j][fid][lane][8e] bf16 (as R3)
__global__ __launch_bounds__(256) void vtrans(const float* __restrict__ p,
                                              ushort_t* __restrict__ vf) {
  __shared__ float tile[8][64][33];
  const int jc = blockIdx.x;
  const int bh = blockIdx.y;
  const int b = bh >> 3, H = bh & 7;
  const int j0 = jc * 8;
  const float* pvb = p + ((size_t)b * 1280 + H * 160 + 128) * 4096;
  const int t = threadIdx.x;
#pragma unroll
  for (int rep = 0; rep < 8; rep++) {
    int idx = rep * 256 + t;
    int d = idx >> 6, i = idx & 63;
    float4 f0 = *(const float4*)&pvb[(size_t)d * 4096 + i * 64 + j0];
    float4 f1 = *(const float4*)&pvb[(size_t)d * 4096 + i * 64 + j0 + 4];
    tile[0][i][d] = f0.x; tile[1][i][d] = f0.y;
    tile[2][i][d] = f0.z; tile[3][i][d] = f0.w;
    tile[4][i][d] = f1.x; tile[5][i][d] = f1.y;
    tile[6][i][d] = f1.z; tile[7][i][d] = f1.w;
  }
  __syncthreads();
  ushort_t* vo = vf + (size_t)bh * 131072;
  const int fid = t >> 6, l = t & 63;
  const int d = (fid & 1) * 16 + (l & 15);
  const int i0 = (fid >> 1) * 32 + (l >> 4) * 8;
#pragma unroll
  for (int rep = 0; rep < 8; rep++) {
    int jl = rep;
    uint4 o;
    o.x = pk2(tile[jl][i0 + 0][d], tile[jl][i0 + 1][d]);
    o.y = pk2(tile[jl][i0 + 2][d], tile[jl][i0 + 3][d]);
    o.z = pk2(tile[jl][i0 + 4][d], tile[jl][i0 + 5][d]);
    o.w = pk2(tile[jl][i0 + 6][d], tile[jl][i0 + 7][d]);
    *(uint4*)&vo[(size_t)(((j0 + jl) * 4 + fid) * 64 + l) * 8] = o;
  }
}

// ---------------- apply v3: LDS-staged Vf, dbuf global_load_lds, j-split by 2.
// block = bh(16) x pg(16) x jc(2); wave = one h row (64 cols), 32 j's in 4 phases.
__global__ __launch_bounds__(256, 2) void attn_apply_v3(const float* __restrict__ p,
                                                        const ushort_t* __restrict__ rs,
                                                        const ushort_t* __restrict__ cs,
                                                        const ushort_t* __restrict__ vf,
                                                        float* __restrict__ out,
                                                        float* __restrict__ pp1) {
  __shared__ ushort_t buf[2][16384];   // 2 x 32 KB, 8 j-records of 4 KB each
  const int bid = blockIdx.x;
  const int jc = bid & 1, pg = (bid >> 1) & 15, bh = bid >> 5;
  const int b = bh >> 3, H = bh & 7;
  const int t = threadIdx.x, wv = t >> 6, l = t & 63;
  const int row = l & 15, quad = l >> 4;
  const int h = pg * 4 + wv;
  const ushort_t* rsl = rs + (size_t)bh * 262144 + (size_t)h * 4096;   // [w][i]
  const ushort_t* csl = cs + (size_t)bh * 262144 + (size_t)h * 4096;   // [a][b]
  const ushort_t* vchunk = vf + (size_t)bh * 131072 + (size_t)jc * 65536;

  // B-fragments (r), loaded once: rf[kc][nf]
  bf16x8 rf[2][4];
#pragma unroll
  for (int nf = 0; nf < 4; nf++)
#pragma unroll
    for (int kc = 0; kc < 2; kc++)
      rf[kc][nf] = *(const bf16x8*)&rsl[(size_t)(nf * 16 + row) * 64 + kc * 32 + quad * 8];

  f32x4 acc[2][4];
#pragma unroll
  for (int i = 0; i < 2; i++)
#pragma unroll
    for (int j = 0; j < 4; j++) acc[i][j] = (f32x4){0.f, 0.f, 0.f, 0.f};

  // stage phase 0
#pragma unroll
  for (int jj = 0; jj < 8; jj++)
    gld16(&vchunk[(size_t)jj * 2048 + wv * 512 + l * 8], &buf[0][jj * 2048 + wv * 512]);
  __syncthreads();

  for (int ph = 0; ph < 4; ph++) {
    const ushort_t* bcur = buf[ph & 1];
    if (ph < 3) {
#pragma unroll
      for (int jj = 0; jj < 8; jj++)
        gld16(&vchunk[(size_t)((ph + 1) * 8 + jj) * 2048 + wv * 512 + l * 8],
              &buf[(ph + 1) & 1][jj * 2048 + wv * 512]);
    }
    float cv[8][4];
#pragma unroll
    for (int jj = 0; jj < 8; jj++)
#pragma unroll
      for (int nf = 0; nf < 4; nf++)
        cv[jj][nf] = bflo((unsigned int)csl[(size_t)(jc * 32 + ph * 8 + jj) * 64 + nf * 16 + row]);
#pragma unroll
    for (int jj = 0; jj < 8; jj++) {
      bf16x8 af0[2], af1[2];
#pragma unroll
      for (int mf = 0; mf < 2; mf++) {
        af0[mf] = *(const bf16x8*)&bcur[jj * 2048 + (0 + mf) * 512 + l * 8];
        af1[mf] = *(const bf16x8*)&bcur[jj * 2048 + (2 + mf) * 512 + l * 8];
      }
#pragma unroll
      for (int mf = 0; mf < 2; mf++)
#pragma unroll
        for (int nf = 0; nf < 4; nf++) {
          f32x4 tt = (f32x4){0.f, 0.f, 0.f, 0.f};
          tt = mfma16(af0[mf], rf[0][nf], tt);
          tt = mfma16(af1[mf], rf[1][nf], tt);
          acc[mf][nf] += tt * cv[jj][nf];
        }
    }
    __syncthreads();   // drains vmcnt (next-phase loads) + all reads of bcur
  }

  if (jc == 0) {
    const float* pv = p + ((size_t)b * 1280 + H * 160 + 128) * 4096 + h * 64;
    float* ob = out + ((size_t)b * 256 + H * 32) * 4096 + h * 64;
#pragma unroll
    for (int mf = 0; mf < 2; mf++)
#pragma unroll
      for (int nf = 0; nf < 4; nf++)
#pragma unroll
        for (int reg = 0; reg < 4; reg++) {
          int d = mf * 16 + quad * 4 + reg;
          int wc = nf * 16 + row;
          ob[(size_t)d * 4096 + wc] = acc[mf][nf][reg] + pv[(size_t)d * 4096 + wc];
        }
  } else {
    float* ob = pp1 + ((size_t)b * 256 + H * 32) * 4096 + h * 64;
#pragma unroll
    for (int mf = 0; mf < 2; mf++)
#pragma unroll
      for (int nf = 0; nf < 4; nf++)
#pragma unroll
        for (int reg = 0; reg < 4; reg++) {
          int d = mf * 16 + quad * 4 + reg;
          int wc = nf * 16 + row;
          ob[(size_t)d * 4096 + wc] = acc[mf][nf][reg];
        }
  }
}

// ---------------- sum_out: out += Pp1
__global__ __launch_bounds__(256) void sum_out(float* __restrict__ out,
                                               const float* __restrict__ pp1) {
  const int idx = (blockIdx.x * 256 + threadIdx.x) * 4;
  float4 a = *(const float4*)&out[idx];
  float4 b = *(const float4*)&pp1[idx];
  a.x += b.x; a.y += b.y; a.z += b.z; a.w += b.w;
  *(float4*)&out[idx] = a;
}

extern "C" void kernel_launch(void* const* d_in, const int* in_sizes, int n_in,
                              void* d_out, int out_size, void* d_ws, size_t ws_size,
                              hipStream_t stream) {
  const float* x = (const float*)d_in[0];
  const float* w = (const float*)d_in[1];
  float* out = (float*)d_out;
  float* ws = (float*)d_ws;
  float* P = ws;
  ushort_t* Rs  = (ushort_t*)(ws + 10485760);
  ushort_t* Cs  = (ushort_t*)(ws + 12582912);
  ushort_t* Vf  = (ushort_t*)(ws + 14680064);
  ushort_t* TQ0 = (ushort_t*)(ws + 15728640);
  ushort_t* TQ1 = (ushort_t*)(ws + 16777216);
  ushort_t* Wbf = (ushort_t*)(ws + 17825792);
  ushort_t* Xt  = (ushort_t*)(ws + 17989632);
  float* Pp1 = ws + 15728640;   // aliases TQ0+TQ1 (dead after col_softmax_v2)

  cvt_w<<<160, 256, 0, stream>>>(w, Wbf);
  xtrans<<<dim3(32, 8, 2), 256, 0, stream>>>(x, Xt);
  proj_mfma<<<dim3(32, 10, 2), 256, 0, stream>>>(Wbf, Xt, P);
  qk_trans<<<dim3(256, 2), 256, 0, stream>>>(P, TQ0, TQ1, 0);
  row_softmax_v2<<<1024, 256, 0, stream>>>(TQ0, TQ1, Rs);
  qk_trans<<<dim3(256, 2), 256, 0, stream>>>(P, TQ0, TQ1, 1);
  col_softmax_v2<<<1024, 256, 0, stream>>>(TQ0, TQ1, Cs);
  vtrans<<<dim3(8, 16), 256, 0, stream>>>(P, Vf);
  attn_apply_v3<<<512, 256, 0, stream>>>(P, Rs, Cs, Vf, out, Pp1);
  sum_out<<<2048, 256, 0, stream>>>(out, Pp1);
}

// Round 5
// 124.869 us; speedup vs baseline: 4.0248x; 1.2647x over previous
//
#include <hip/hip_runtime.h>
#include <stdint.h>

// MatrixAttentionFunc: b=2, NH=8, KD=HD=32, D=256, 64x64 spatial.
// R5: proj writes Qr/Kr/Qc/Kc bf16 + P_v fp32 directly (qk_trans deleted);
//     row+col softmax = one MFMA kernel (frags direct from global, no LDS GEMM);
//     Cs layout [h][b][a] so apply reads c as uint4.
//
// ws layout (float units), total 14,843,904 fu = 59.4 MB:
//   P_v  [bh][32][4096] fp32       @ 0          ( 2,097,152)
//   Rs   [bh][h][w][i]  bf16       @ 2097152    ( 2,097,152)
//   Cs   [bh][h][b][a]  bf16       @ 4194304    ( 2,097,152)
//   Vf   [bh][j][fid][lane][8] bf16@ 6291456    ( 1,048,576)
//   Qr   [bh][w*64+h][32d] bf16    @ 7340032    ( 1,048,576)
//   Kr   "                         @ 8388608    ( 1,048,576)
//   Qc   [bh][h*64+w][32d] bf16    @ 9437184    ( 1,048,576)
//   Kc   "                         @ 10485760   ( 1,048,576)
//   Wbf  [1280][256]    bf16       @ 11534336   (   163,840)
//   Xt   [2][4096][256] bf16       @ 11698176   ( 1,048,576)
//   Pp1  [bh][32][4096] fp32       @ 12746752   ( 2,097,152)

#define SCALE 0.17677669529663687f
typedef unsigned short ushort_t;
typedef __attribute__((ext_vector_type(8))) short bf16x8;
typedef __attribute__((ext_vector_type(4))) float f32x4;

__device__ __forceinline__ unsigned short f2bf(float f) {
  unsigned int b = __float_as_uint(f);
  b += 0x7fffu + ((b >> 16) & 1u);
  return (unsigned short)(b >> 16);
}
__device__ __forceinline__ float bflo(unsigned int u) { return __uint_as_float(u << 16); }
__device__ __forceinline__ float bfhi(unsigned int u) { return __uint_as_float(u & 0xffff0000u); }
__device__ __forceinline__ unsigned int pk2(float a, float b) {
  return (unsigned int)f2bf(a) | ((unsigned int)f2bf(b) << 16);
}
__device__ __forceinline__ f32x4 mfma16(bf16x8 a, bf16x8 b, f32x4 c) {
  return __builtin_amdgcn_mfma_f32_16x16x32_bf16(a, b, c, 0, 0, 0);
}
__device__ __forceinline__ void gld16(const void* g, void* l) {
  __builtin_amdgcn_global_load_lds(
      (const __attribute__((address_space(1))) unsigned int*)g,
      (__attribute__((address_space(3))) unsigned int*)l, 16, 0, 0);
}

// ---------------- cvt_w: W fp32 -> bf16
__global__ __launch_bounds__(256) void cvt_w(const float* __restrict__ w,
                                             ushort_t* __restrict__ wbf) {
  const int idx = (blockIdx.x * 256 + threadIdx.x) * 8;
  float4 f0 = *(const float4*)&w[idx];
  float4 f1 = *(const float4*)&w[idx + 4];
  uint4 o; o.x = pk2(f0.x, f0.y); o.y = pk2(f0.z, f0.w);
  o.z = pk2(f1.x, f1.y); o.w = pk2(f1.z, f1.w);
  *(uint4*)&wbf[idx] = o;
}

// ---------------- xtrans: X[b][k][n] fp32 -> Xt[b][n][k] bf16
__global__ __launch_bounds__(256) void xtrans(const float* __restrict__ x,
                                              ushort_t* __restrict__ xt) {
  __shared__ float tile[128][33];
  const int b = blockIdx.z, k0 = blockIdx.y * 32, n0 = blockIdx.x * 128;
  const int t = threadIdx.x;
  const float* xb = x + (size_t)b * 256 * 4096;
#pragma unroll
  for (int rep = 0; rep < 4; rep++) {
    int idx = rep * 256 + t;
    int kk = idx >> 5, nn4 = (idx & 31) * 4;
    float4 f = *(const float4*)&xb[(size_t)(k0 + kk) * 4096 + n0 + nn4];
    tile[nn4 + 0][kk] = f.x; tile[nn4 + 1][kk] = f.y;
    tile[nn4 + 2][kk] = f.z; tile[nn4 + 3][kk] = f.w;
  }
  __syncthreads();
  ushort_t* xo = xt + (size_t)b * 4096 * 256;
#pragma unroll
  for (int rep = 0; rep < 2; rep++) {
    int idx = rep * 256 + t;
    int n = idx >> 2, k8 = (idx & 3) * 8;
    uint4 o;
    o.x = pk2(tile[n][k8 + 0], tile[n][k8 + 1]);
    o.y = pk2(tile[n][k8 + 2], tile[n][k8 + 3]);
    o.z = pk2(tile[n][k8 + 4], tile[n][k8 + 5]);
    o.w = pk2(tile[n][k8 + 6], tile[n][k8 + 7]);
    *(uint4*)&xo[(size_t)(n0 + n) * 256 + k0 + k8] = o;
  }
}

// ---------------- proj v2: MFMA GEMM; epilogue routes q/k -> bf16 frag buffers,
// v -> P_v fp32. Section/head routing is wave-uniform (32-aligned boundaries).
__global__ __launch_bounds__(256, 2) void proj_mfma_v2(const ushort_t* __restrict__ wbf,
                                                       const ushort_t* __restrict__ xt,
                                                       ushort_t* __restrict__ Qr,
                                                       ushort_t* __restrict__ Kr,
                                                       ushort_t* __restrict__ Qc,
                                                       ushort_t* __restrict__ Kc,
                                                       float* __restrict__ P_v) {
  __shared__ ushort_t Af[8 * 64 * 8];
  __shared__ ushort_t Bf[8 * 64 * 8];
  const int b = blockIdx.z, m0 = blockIdx.y * 128, n0 = blockIdx.x * 128;
  const int t = threadIdx.x, wv = t >> 6, l = t & 63;
  const int row = l & 15, quad = l >> 4;
  const int wm = wv >> 1, wn = wv & 1;
  const ushort_t* xb = xt + (size_t)b * 4096 * 256;

  f32x4 acc[4][4];
#pragma unroll
  for (int i = 0; i < 4; i++)
#pragma unroll
    for (int j = 0; j < 4; j++) acc[i][j] = (f32x4){0.f, 0.f, 0.f, 0.f};

  const size_t aoff0 = (size_t)(m0 + (2 * wv + 0) * 16 + row) * 256 + quad * 8;
  const size_t aoff1 = (size_t)(m0 + (2 * wv + 1) * 16 + row) * 256 + quad * 8;
  const size_t boff0 = (size_t)(n0 + (2 * wv + 0) * 16 + row) * 256 + quad * 8;
  const size_t boff1 = (size_t)(n0 + (2 * wv + 1) * 16 + row) * 256 + quad * 8;

  for (int k0 = 0; k0 < 256; k0 += 32) {
    uint4 a0 = *(const uint4*)&wbf[aoff0 + k0];
    uint4 a1 = *(const uint4*)&wbf[aoff1 + k0];
    uint4 b0 = *(const uint4*)&xb[boff0 + k0];
    uint4 b1 = *(const uint4*)&xb[boff1 + k0];
    __syncthreads();
    *(uint4*)&Af[((2 * wv + 0) * 64 + l) * 8] = a0;
    *(uint4*)&Af[((2 * wv + 1) * 64 + l) * 8] = a1;
    *(uint4*)&Bf[((2 * wv + 0) * 64 + l) * 8] = b0;
    *(uint4*)&Bf[((2 * wv + 1) * 64 + l) * 8] = b1;
    __syncthreads();
    bf16x8 af[4], bfr[4];
#pragma unroll
    for (int mf = 0; mf < 4; mf++) af[mf] = *(bf16x8*)&Af[((wm * 4 + mf) * 64 + l) * 8];
#pragma unroll
    for (int nf = 0; nf < 4; nf++) bfr[nf] = *(bf16x8*)&Bf[((wn * 4 + nf) * 64 + l) * 8];
#pragma unroll
    for (int mf = 0; mf < 4; mf++)
#pragma unroll
      for (int nf = 0; nf < 4; nf++)
        acc[mf][nf] = mfma16(af[mf], bfr[nf], acc[mf][nf]);
  }

  // epilogue: m -> (H, sec, d). sec 0..3 = rq,rk,cq,ck (bf16 frag buffers);
  // sec 4 = v (fp32 P_v). All 4 regs of a group share (H, sec).
#pragma unroll
  for (int mf = 0; mf < 4; mf++) {
    int mb = m0 + wm * 64 + mf * 16 + quad * 4;
    int H = mb / 160;
    int rem = mb - H * 160;
    int sec = rem >> 5;
    int d0 = rem & 31;
    int bh = b * 8 + H;
    if (sec < 4) {
      ushort_t* base = (sec == 0) ? Qr : (sec == 1) ? Kr : (sec == 2) ? Qc : Kc;
      base += (size_t)bh * 131072;
#pragma unroll
      for (int nf = 0; nf < 4; nf++) {
        int n = n0 + wn * 64 + nf * 16 + row;
        int orow = (sec < 2) ? ((n & 63) * 64 + (n >> 6)) : n;
        uint2 o;
        o.x = pk2(acc[mf][nf][0], acc[mf][nf][1]);
        o.y = pk2(acc[mf][nf][2], acc[mf][nf][3]);
        *(uint2*)&base[(size_t)orow * 32 + d0] = o;
      }
    } else {
      float* pvb = P_v + ((size_t)bh * 32 + d0) * 4096;
#pragma unroll
      for (int nf = 0; nf < 4; nf++) {
        int n = n0 + wn * 64 + nf * 16 + row;
#pragma unroll
        for (int r = 0; r < 4; r++)
          pvb[(size_t)r * 4096 + n] = acc[mf][nf][r];
      }
    }
  }
}

// ---------------- scores: MFMA QK^T + softmax over i (C-layout rows).
// mode 0: Qr/Kr (g=w) -> Rs[bh][j][g][i];  mode 1: Qc/Kc (g=h) -> Cs[bh][g][j][i].
// Fragments load directly from global; softmax reduce = in-reg + shfl_xor(16,32).
__global__ __launch_bounds__(256) void scores_mfma(const ushort_t* __restrict__ Qr,
                                                   const ushort_t* __restrict__ Kr,
                                                   const ushort_t* __restrict__ Qc,
                                                   const ushort_t* __restrict__ Kc,
                                                   ushort_t* __restrict__ Rs,
                                                   ushort_t* __restrict__ Cs) {
  const int mode = blockIdx.y;
  const int bh = blockIdx.x >> 4, gq = blockIdx.x & 15;
  const int t = threadIdx.x, wv = t >> 6, l = t & 63;
  const int col = l & 15, quad = l >> 4;
  const int g = gq * 4 + wv;
  const ushort_t* Qb = (mode ? Qc : Qr) + (size_t)bh * 131072 + (size_t)g * 2048;
  const ushort_t* Kb = (mode ? Kc : Kr) + (size_t)bh * 131072 + (size_t)g * 2048;

  bf16x8 aq[4], bk[4];
#pragma unroll
  for (int f = 0; f < 4; f++) {
    aq[f] = *(const bf16x8*)&Qb[(size_t)(f * 16 + col) * 32 + quad * 8];
    bk[f] = *(const bf16x8*)&Kb[(size_t)(f * 16 + col) * 32 + quad * 8];
  }
  f32x4 s[4][4];
#pragma unroll
  for (int i0 = 0; i0 < 4; i0++)
#pragma unroll
    for (int j0 = 0; j0 < 4; j0++)
      s[i0][j0] = mfma16(aq[i0], bk[j0], (f32x4){0.f, 0.f, 0.f, 0.f});

  ushort_t* ob = (mode ? Cs : Rs) + (size_t)bh * 262144;
#pragma unroll
  for (int j0 = 0; j0 < 4; j0++) {
    float sv[16];
#pragma unroll
    for (int i0 = 0; i0 < 4; i0++)
#pragma unroll
      for (int r = 0; r < 4; r++) sv[i0 * 4 + r] = s[i0][j0][r] * SCALE;
    float mx = sv[0];
#pragma unroll
    for (int q = 1; q < 16; q++) mx = fmaxf(mx, sv[q]);
    mx = fmaxf(mx, __shfl_xor(mx, 16));
    mx = fmaxf(mx, __shfl_xor(mx, 32));
    float e[16], sum = 0.f;
#pragma unroll
    for (int q = 0; q < 16; q++) { e[q] = __expf(sv[q] - mx); sum += e[q]; }
    sum += __shfl_xor(sum, 16);
    sum += __shfl_xor(sum, 32);
    const float inv = 1.f / sum;
    const int j = j0 * 16 + col;
#pragma unroll
    for (int i0 = 0; i0 < 4; i0++) {
      uint2 o;
      o.x = pk2(e[i0 * 4 + 0] * inv, e[i0 * 4 + 1] * inv);
      o.y = pk2(e[i0 * 4 + 2] * inv, e[i0 * 4 + 3] * inv);
      size_t addr = mode ? ((size_t)(g * 64 + j) * 64 + i0 * 16 + quad * 4)
                         : ((size_t)(j * 64 + g) * 64 + i0 * 16 + quad * 4);
      *(uint2*)&ob[addr] = o;
    }
  }
}

// ---------------- vtrans: P_v[bh][d][i*64+j] -> Vf[bh][j][fid][lane][8e] bf16
__global__ __launch_bounds__(256) void vtrans(const float* __restrict__ P_v,
                                              ushort_t* __restrict__ vf) {
  __shared__ float tile[8][64][33];
  const int jc = blockIdx.x;
  const int bh = blockIdx.y;
  const int j0 = jc * 8;
  const float* pvb = P_v + (size_t)bh * 131072;
  const int t = threadIdx.x;
#pragma unroll
  for (int rep = 0; rep < 8; rep++) {
    int idx = rep * 256 + t;
    int d = idx >> 6, i = idx & 63;
    float4 f0 = *(const float4*)&pvb[(size_t)d * 4096 + i * 64 + j0];
    float4 f1 = *(const float4*)&pvb[(size_t)d * 4096 + i * 64 + j0 + 4];
    tile[0][i][d] = f0.x; tile[1][i][d] = f0.y;
    tile[2][i][d] = f0.z; tile[3][i][d] = f0.w;
    tile[4][i][d] = f1.x; tile[5][i][d] = f1.y;
    tile[6][i][d] = f1.z; tile[7][i][d] = f1.w;
  }
  __syncthreads();
  ushort_t* vo = vf + (size_t)bh * 131072;
  const int fid = t >> 6, l = t & 63;
  const int d = (fid & 1) * 16 + (l & 15);
  const int i0 = (fid >> 1) * 32 + (l >> 4) * 8;
#pragma unroll
  for (int rep = 0; rep < 8; rep++) {
    int jl = rep;
    uint4 o;
    o.x = pk2(tile[jl][i0 + 0][d], tile[jl][i0 + 1][d]);
    o.y = pk2(tile[jl][i0 + 2][d], tile[jl][i0 + 3][d]);
    o.z = pk2(tile[jl][i0 + 4][d], tile[jl][i0 + 5][d]);
    o.w = pk2(tile[jl][i0 + 6][d], tile[jl][i0 + 7][d]);
    *(uint4*)&vo[(size_t)(((j0 + jl) * 4 + fid) * 64 + l) * 8] = o;
  }
}

// ---------------- apply v4: LDS-staged Vf (dbuf gld16), j-split by 2,
// Cs reads vectorized (uint4 of 8 contiguous a's per nf per phase).
__global__ __launch_bounds__(256, 2) void attn_apply_v4(const float* __restrict__ P_v,
                                                        const ushort_t* __restrict__ rs,
                                                        const ushort_t* __restrict__ cs,
                                                        const ushort_t* __restrict__ vf,
                                                        float* __restrict__ out,
                                                        float* __restrict__ pp1) {
  __shared__ ushort_t buf[2][16384];   // 2 x 32 KB, 8 j-records of 4 KB each
  const int bid = blockIdx.x;
  const int jc = bid & 1, pg = (bid >> 1) & 15, bh = bid >> 5;
  const int b = bh >> 3, H = bh & 7;
  const int t = threadIdx.x, wv = t >> 6, l = t & 63;
  const int row = l & 15, quad = l >> 4;
  const int h = pg * 4 + wv;
  const ushort_t* rsl = rs + (size_t)bh * 262144 + (size_t)h * 4096;   // [w][i]
  const ushort_t* csl = cs + (size_t)bh * 262144 + (size_t)h * 4096;   // [b][a]
  const ushort_t* vchunk = vf + (size_t)bh * 131072 + (size_t)jc * 65536;

  bf16x8 rf[2][4];
#pragma unroll
  for (int nf = 0; nf < 4; nf++)
#pragma unroll
    for (int kc = 0; kc < 2; kc++)
      rf[kc][nf] = *(const bf16x8*)&rsl[(size_t)(nf * 16 + row) * 64 + kc * 32 + quad * 8];

  f32x4 acc[2][4];
#pragma unroll
  for (int i = 0; i < 2; i++)
#pragma unroll
    for (int j = 0; j < 4; j++) acc[i][j] = (f32x4){0.f, 0.f, 0.f, 0.f};

#pragma unroll
  for (int jj = 0; jj < 8; jj++)
    gld16(&vchunk[(size_t)jj * 2048 + wv * 512 + l * 8], &buf[0][jj * 2048 + wv * 512]);
  __syncthreads();

  for (int ph = 0; ph < 4; ph++) {
    const ushort_t* bcur = buf[ph & 1];
    if (ph < 3) {
#pragma unroll
      for (int jj = 0; jj < 8; jj++)
        gld16(&vchunk[(size_t)((ph + 1) * 8 + jj) * 2048 + wv * 512 + l * 8],
              &buf[(ph + 1) & 1][jj * 2048 + wv * 512]);
    }
    float cv[8][4];
#pragma unroll
    for (int nf = 0; nf < 4; nf++) {
      uint4 u = *(const uint4*)&csl[(size_t)(nf * 16 + row) * 64 + jc * 32 + ph * 8];
      cv[0][nf] = bflo(u.x); cv[1][nf] = bfhi(u.x);
      cv[2][nf] = bflo(u.y); cv[3][nf] = bfhi(u.y);
      cv[4][nf] = bflo(u.z); cv[5][nf] = bfhi(u.z);
      cv[6][nf] = bflo(u.w); cv[7][nf] = bfhi(u.w);
    }
#pragma unroll
    for (int jj = 0; jj < 8; jj++) {
      bf16x8 af0[2], af1[2];
#pragma unroll
      for (int mf = 0; mf < 2; mf++) {
        af0[mf] = *(const bf16x8*)&bcur[jj * 2048 + (0 + mf) * 512 + l * 8];
        af1[mf] = *(const bf16x8*)&bcur[jj * 2048 + (2 + mf) * 512 + l * 8];
      }
#pragma unroll
      for (int mf = 0; mf < 2; mf++)
#pragma unroll
        for (int nf = 0; nf < 4; nf++) {
          f32x4 tt = (f32x4){0.f, 0.f, 0.f, 0.f};
          tt = mfma16(af0[mf], rf[0][nf], tt);
          tt = mfma16(af1[mf], rf[1][nf], tt);
          acc[mf][nf] += tt * cv[jj][nf];
        }
    }
    __syncthreads();
  }

  if (jc == 0) {
    const float* pv = P_v + (size_t)bh * 131072 + h * 64;
    float* ob = out + ((size_t)b * 256 + H * 32) * 4096 + h * 64;
#pragma unroll
    for (int mf = 0; mf < 2; mf++)
#pragma unroll
      for (int nf = 0; nf < 4; nf++)
#pragma unroll
        for (int reg = 0; reg < 4; reg++) {
          int d = mf * 16 + quad * 4 + reg;
          int wc = nf * 16 + row;
          ob[(size_t)d * 4096 + wc] = acc[mf][nf][reg] + pv[(size_t)d * 4096 + wc];
        }
  } else {
    float* ob = pp1 + (size_t)bh * 131072 + h * 64;
#pragma unroll
    for (int mf = 0; mf < 2; mf++)
#pragma unroll
      for (int nf = 0; nf < 4; nf++)
#pragma unroll
        for (int reg = 0; reg < 4; reg++) {
          int d = mf * 16 + quad * 4 + reg;
          int wc = nf * 16 + row;
          ob[(size_t)d * 4096 + wc] = acc[mf][nf][reg];
        }
  }
}

// ---------------- sum_out: out += Pp1 (Pp1 is [bh][32][4096] = same flat order as out)
__global__ __launch_bounds__(256) void sum_out(float* __restrict__ out,
                                               const float* __restrict__ pp1) {
  const int idx = (blockIdx.x * 256 + threadIdx.x) * 4;
  float4 a = *(const float4*)&out[idx];
  float4 b = *(const float4*)&pp1[idx];
  a.x += b.x; a.y += b.y; a.z += b.z; a.w += b.w;
  *(float4*)&out[idx] = a;
}

extern "C" void kernel_launch(void* const* d_in, const int* in_sizes, int n_in,
                              void* d_out, int out_size, void* d_ws, size_t ws_size,
                              hipStream_t stream) {
  const float* x = (const float*)d_in[0];
  const float* w = (const float*)d_in[1];
  float* out = (float*)d_out;
  float* ws = (float*)d_ws;
  float* P_v = ws;                                  //  2,097,152 fu
  ushort_t* Rs  = (ushort_t*)(ws + 2097152);        //  2,097,152 fu
  ushort_t* Cs  = (ushort_t*)(ws + 4194304);        //  2,097,152 fu
  ushort_t* Vf  = (ushort_t*)(ws + 6291456);        //  1,048,576 fu
  ushort_t* Qr  = (ushort_t*)(ws + 7340032);        //  1,048,576 fu
  ushort_t* Kr  = (ushort_t*)(ws + 8388608);        //  1,048,576 fu
  ushort_t* Qc  = (ushort_t*)(ws + 9437184);        //  1,048,576 fu
  ushort_t* Kc  = (ushort_t*)(ws + 10485760);       //  1,048,576 fu
  ushort_t* Wbf = (ushort_t*)(ws + 11534336);       //    163,840 fu
  ushort_t* Xt  = (ushort_t*)(ws + 11698176);       //  1,048,576 fu
  float* Pp1 = ws + 12746752;                       //  2,097,152 fu

  cvt_w<<<160, 256, 0, stream>>>(w, Wbf);
  xtrans<<<dim3(32, 8, 2), 256, 0, stream>>>(x, Xt);
  proj_mfma_v2<<<dim3(32, 10, 2), 256, 0, stream>>>(Wbf, Xt, Qr, Kr, Qc, Kc, P_v);
  scores_mfma<<<dim3(256, 2), 256, 0, stream>>>(Qr, Kr, Qc, Kc, Rs, Cs);
  vtrans<<<dim3(8, 16), 256, 0, stream>>>(P_v, Vf);
  attn_apply_v4<<<512, 256, 0, stream>>>(P_v, Rs, Cs, Vf, out, Pp1);
  sum_out<<<2048, 256, 0, stream>>>(out, Pp1);
}

// Round 6
// 120.128 us; speedup vs baseline: 4.1836x; 1.0395x over previous
//
#include <hip/hip_runtime.h>
#include <stdint.h>

// MatrixAttentionFunc: b=2, NH=8, KD=HD=32, D=256, 64x64 spatial.
// R6: proj = LDS-free barrier-free direct-fragment MFMA GEMM (W/X pre-stored in
//     fragment order by prep); scores+vtrans merged; 5 launches total.
//
// ws layout (float units), total 14,843,904 fu = 59.4 MB:
//   P_v  [bh][32][4096] fp32       @ 0          ( 2,097,152)
//   Rs   [bh][h][w][i]  bf16       @ 2097152    ( 2,097,152)
//   Cs   [bh][h][b][a]  bf16       @ 4194304    ( 2,097,152)
//   Vf   [bh][j][fid][lane][8] bf16@ 6291456    ( 1,048,576)
//   Qr   [bh][w*64+h][32d] bf16    @ 7340032    ( 1,048,576)
//   Kr   "                         @ 8388608    ( 1,048,576)
//   Qc   [bh][h*64+w][32d] bf16    @ 9437184    ( 1,048,576)
//   Kc   "                         @ 10485760   ( 1,048,576)
//   Wf   [mt*8+kc][64l][8e] bf16   @ 11534336   (   163,840)  A-frag order
//   Xtf  [b][nt*8+kc][64l][8e] bf16@ 11698176   ( 1,048,576)  B-frag order
//   Pp1  [bh][32][4096] fp32       @ 12746752   ( 2,097,152)

#define SCALE 0.17677669529663687f
typedef unsigned short ushort_t;
typedef __attribute__((ext_vector_type(8))) short bf16x8;
typedef __attribute__((ext_vector_type(4))) float f32x4;

__device__ __forceinline__ unsigned short f2bf(float f) {
  unsigned int b = __float_as_uint(f);
  b += 0x7fffu + ((b >> 16) & 1u);
  return (unsigned short)(b >> 16);
}
__device__ __forceinline__ float bflo(unsigned int u) { return __uint_as_float(u << 16); }
__device__ __forceinline__ float bfhi(unsigned int u) { return __uint_as_float(u & 0xffff0000u); }
__device__ __forceinline__ unsigned int pk2(float a, float b) {
  return (unsigned int)f2bf(a) | ((unsigned int)f2bf(b) << 16);
}
__device__ __forceinline__ f32x4 mfma16(bf16x8 a, bf16x8 b, f32x4 c) {
  return __builtin_amdgcn_mfma_f32_16x16x32_bf16(a, b, c, 0, 0, 0);
}
__device__ __forceinline__ void gld16(const void* g, void* l) {
  __builtin_amdgcn_global_load_lds(
      (const __attribute__((address_space(1))) unsigned int*)g,
      (__attribute__((address_space(3))) unsigned int*)l, 16, 0, 0);
}

// ---------------- prep: bid<512 -> X fp32 -> Xtf (B-frag order bf16);
//                  bid>=512 -> W fp32 -> Wf (A-frag order bf16), mt = bid-512.
__global__ __launch_bounds__(256) void prep(const float* __restrict__ x,
                                            const float* __restrict__ w,
                                            ushort_t* __restrict__ xtf,
                                            ushort_t* __restrict__ wf) {
  const int bid = blockIdx.x;
  const int t = threadIdx.x;
  if (bid < 512) {
    __shared__ float tile[128][33];
    const int b = bid >> 8, rem = bid & 255;
    const int kc = rem >> 5;              // k0 = kc*32
    const int n0 = (rem & 31) * 128;
    const float* xb = x + (size_t)b * 256 * 4096;
#pragma unroll
    for (int rep = 0; rep < 4; rep++) {
      int idx = rep * 256 + t;
      int kk = idx >> 5, nn4 = (idx & 31) * 4;
      float4 f = *(const float4*)&xb[(size_t)(kc * 32 + kk) * 4096 + n0 + nn4];
      tile[nn4 + 0][kk] = f.x; tile[nn4 + 1][kk] = f.y;
      tile[nn4 + 2][kk] = f.z; tile[nn4 + 3][kk] = f.w;
    }
    __syncthreads();
    ushort_t* xo = xtf + (size_t)b * 1048576;
#pragma unroll
    for (int rep = 0; rep < 2; rep++) {
      int idx = rep * 256 + t;
      int n = idx >> 2, k8 = (idx & 3) * 8;       // n local 0..127, k8 in {0,8,16,24}
      uint4 o;
      o.x = pk2(tile[n][k8 + 0], tile[n][k8 + 1]);
      o.y = pk2(tile[n][k8 + 2], tile[n][k8 + 3]);
      o.z = pk2(tile[n][k8 + 4], tile[n][k8 + 5]);
      o.w = pk2(tile[n][k8 + 6], tile[n][k8 + 7]);
      int nt = (n0 + n) >> 4;
      int lane = ((n0 + n) & 15) + ((k8 >> 3) << 4);
      *(uint4*)&xo[(size_t)((nt * 8 + kc) * 64 + lane) * 8] = o;
    }
  } else {
    const int mt = bid - 512;             // 0..79
    const int wv = t >> 6, l = t & 63;
#pragma unroll
    for (int s = 0; s < 2; s++) {
      int kc = wv + s * 4;
      const float* src = &w[(size_t)(mt * 16 + (l & 15)) * 256 + kc * 32 + (l >> 4) * 8];
      float4 f0 = *(const float4*)&src[0];
      float4 f1 = *(const float4*)&src[4];
      uint4 o;
      o.x = pk2(f0.x, f0.y); o.y = pk2(f0.z, f0.w);
      o.z = pk2(f1.x, f1.y); o.w = pk2(f1.z, f1.w);
      *(uint4*)&wf[(size_t)((mt * 8 + kc) * 64 + l) * 8] = o;
    }
  }
}

// ---------------- proj v3: direct-fragment MFMA GEMM. No LDS, no barriers.
// A/B frags are single coalesced dwordx4 loads from Wf/Xtf (L2-resident).
__global__ __launch_bounds__(256, 4) void proj_mfma_v3(const ushort_t* __restrict__ wf,
                                                       const ushort_t* __restrict__ xtf,
                                                       ushort_t* __restrict__ Qr,
                                                       ushort_t* __restrict__ Kr,
                                                       ushort_t* __restrict__ Qc,
                                                       ushort_t* __restrict__ Kc,
                                                       float* __restrict__ P_v) {
  const int b = blockIdx.z, by = blockIdx.y, bx = blockIdx.x;
  const int m0 = by * 128, n0 = bx * 128;
  const int t = threadIdx.x, wv = t >> 6, l = t & 63;
  const int row = l & 15, quad = l >> 4;
  const int wm = wv >> 1, wn = wv & 1;
  const ushort_t* xb = xtf + (size_t)b * 1048576;

  f32x4 acc[4][4];
#pragma unroll
  for (int i = 0; i < 4; i++)
#pragma unroll
    for (int j = 0; j < 4; j++) acc[i][j] = (f32x4){0.f, 0.f, 0.f, 0.f};

  const size_t abase = (size_t)(by * 8 + wm * 4) * 4096 + l * 8;
  const size_t bbase = (size_t)(bx * 8 + wn * 4) * 4096 + l * 8;

  for (int kc = 0; kc < 8; kc++) {
    bf16x8 af[4], bfr[4];
#pragma unroll
    for (int mf = 0; mf < 4; mf++)
      af[mf] = *(const bf16x8*)&wf[abase + mf * 4096 + kc * 512];
#pragma unroll
    for (int nf = 0; nf < 4; nf++)
      bfr[nf] = *(const bf16x8*)&xb[bbase + nf * 4096 + kc * 512];
#pragma unroll
    for (int mf = 0; mf < 4; mf++)
#pragma unroll
      for (int nf = 0; nf < 4; nf++)
        acc[mf][nf] = mfma16(af[mf], bfr[nf], acc[mf][nf]);
  }

  // epilogue: m -> (H, sec, d). sec 0..3 = rq,rk,cq,ck (bf16 frag buffers);
  // sec 4 = v (fp32 P_v). All 4 regs of a group share (H, sec).
#pragma unroll
  for (int mf = 0; mf < 4; mf++) {
    int mb = m0 + wm * 64 + mf * 16 + quad * 4;
    int H = mb / 160;
    int rem = mb - H * 160;
    int sec = rem >> 5;
    int d0 = rem & 31;
    int bh = b * 8 + H;
    if (sec < 4) {
      ushort_t* base = (sec == 0) ? Qr : (sec == 1) ? Kr : (sec == 2) ? Qc : Kc;
      base += (size_t)bh * 131072;
#pragma unroll
      for (int nf = 0; nf < 4; nf++) {
        int n = n0 + wn * 64 + nf * 16 + row;
        int orow = (sec < 2) ? ((n & 63) * 64 + (n >> 6)) : n;
        uint2 o;
        o.x = pk2(acc[mf][nf][0], acc[mf][nf][1]);
        o.y = pk2(acc[mf][nf][2], acc[mf][nf][3]);
        *(uint2*)&base[(size_t)orow * 32 + d0] = o;
      }
    } else {
      float* pvb = P_v + ((size_t)bh * 32 + d0) * 4096;
#pragma unroll
      for (int nf = 0; nf < 4; nf++) {
        int n = n0 + wn * 64 + nf * 16 + row;
#pragma unroll
        for (int r = 0; r < 4; r++)
          pvb[(size_t)r * 4096 + n] = acc[mf][nf][r];
      }
    }
  }
}

// ---------------- mid: bid<512 -> scores (mode = bid>>8); bid>=512 -> vtrans.
__global__ __launch_bounds__(256) void mid(const ushort_t* __restrict__ Qr,
                                           const ushort_t* __restrict__ Kr,
                                           const ushort_t* __restrict__ Qc,
                                           const ushort_t* __restrict__ Kc,
                                           ushort_t* __restrict__ Rs,
                                           ushort_t* __restrict__ Cs,
                                           const float* __restrict__ P_v,
                                           ushort_t* __restrict__ vf) {
  __shared__ float tile[8][64][33];
  const int bid = blockIdx.x;
  const int t = threadIdx.x, wv = t >> 6, l = t & 63;
  if (bid < 512) {
    // ---- scores: MFMA QK^T + softmax over i (C-layout rows), frags from global
    const int mode = bid >> 8;
    const int idx = bid & 255;
    const int bh = idx >> 4, gq = idx & 15;
    const int col = l & 15, quad = l >> 4;
    const int g = gq * 4 + wv;
    const ushort_t* Qb = (mode ? Qc : Qr) + (size_t)bh * 131072 + (size_t)g * 2048;
    const ushort_t* Kb = (mode ? Kc : Kr) + (size_t)bh * 131072 + (size_t)g * 2048;

    bf16x8 aq[4], bk[4];
#pragma unroll
    for (int f = 0; f < 4; f++) {
      aq[f] = *(const bf16x8*)&Qb[(size_t)(f * 16 + col) * 32 + quad * 8];
      bk[f] = *(const bf16x8*)&Kb[(size_t)(f * 16 + col) * 32 + quad * 8];
    }
    f32x4 s[4][4];
#pragma unroll
    for (int i0 = 0; i0 < 4; i0++)
#pragma unroll
      for (int j0 = 0; j0 < 4; j0++)
        s[i0][j0] = mfma16(aq[i0], bk[j0], (f32x4){0.f, 0.f, 0.f, 0.f});

    ushort_t* ob = (mode ? Cs : Rs) + (size_t)bh * 262144;
#pragma unroll
    for (int j0 = 0; j0 < 4; j0++) {
      float sv[16];
#pragma unroll
      for (int i0 = 0; i0 < 4; i0++)
#pragma unroll
        for (int r = 0; r < 4; r++) sv[i0 * 4 + r] = s[i0][j0][r] * SCALE;
      float mx = sv[0];
#pragma unroll
      for (int q = 1; q < 16; q++) mx = fmaxf(mx, sv[q]);
      mx = fmaxf(mx, __shfl_xor(mx, 16));
      mx = fmaxf(mx, __shfl_xor(mx, 32));
      float e[16], sum = 0.f;
#pragma unroll
      for (int q = 0; q < 16; q++) { e[q] = __expf(sv[q] - mx); sum += e[q]; }
      sum += __shfl_xor(sum, 16);
      sum += __shfl_xor(sum, 32);
      const float inv = 1.f / sum;
      const int j = j0 * 16 + col;
#pragma unroll
      for (int i0 = 0; i0 < 4; i0++) {
        uint2 o;
        o.x = pk2(e[i0 * 4 + 0] * inv, e[i0 * 4 + 1] * inv);
        o.y = pk2(e[i0 * 4 + 2] * inv, e[i0 * 4 + 3] * inv);
        size_t addr = mode ? ((size_t)(g * 64 + j) * 64 + i0 * 16 + quad * 4)
                           : ((size_t)(j * 64 + g) * 64 + i0 * 16 + quad * 4);
        *(uint2*)&ob[addr] = o;
      }
    }
  } else {
    // ---- vtrans: P_v[bh][d][i*64+j] -> Vf[bh][j][fid][lane][8e] bf16
    const int vid = bid - 512;
    const int jc = vid & 7, bh = vid >> 3;
    const int j0 = jc * 8;
    const float* pvb = P_v + (size_t)bh * 131072;
#pragma unroll
    for (int rep = 0; rep < 8; rep++) {
      int idx = rep * 256 + t;
      int d = idx >> 6, i = idx & 63;
      float4 f0 = *(const float4*)&pvb[(size_t)d * 4096 + i * 64 + j0];
      float4 f1 = *(const float4*)&pvb[(size_t)d * 4096 + i * 64 + j0 + 4];
      tile[0][i][d] = f0.x; tile[1][i][d] = f0.y;
      tile[2][i][d] = f0.z; tile[3][i][d] = f0.w;
      tile[4][i][d] = f1.x; tile[5][i][d] = f1.y;
      tile[6][i][d] = f1.z; tile[7][i][d] = f1.w;
    }
    __syncthreads();
    ushort_t* vo = vf + (size_t)bh * 131072;
    const int fid = t >> 6;
    const int d = (fid & 1) * 16 + (l & 15);
    const int i0 = (fid >> 1) * 32 + (l >> 4) * 8;
#pragma unroll
    for (int rep = 0; rep < 8; rep++) {
      int jl = rep;
      uint4 o;
      o.x = pk2(tile[jl][i0 + 0][d], tile[jl][i0 + 1][d]);
      o.y = pk2(tile[jl][i0 + 2][d], tile[jl][i0 + 3][d]);
      o.z = pk2(tile[jl][i0 + 4][d], tile[jl][i0 + 5][d]);
      o.w = pk2(tile[jl][i0 + 6][d], tile[jl][i0 + 7][d]);
      *(uint4*)&vo[(size_t)(((j0 + jl) * 4 + fid) * 64 + l) * 8] = o;
    }
  }
}

// ---------------- apply v4: LDS-staged Vf (dbuf gld16), j-split by 2.
__global__ __launch_bounds__(256, 2) void attn_apply_v4(const float* __restrict__ P_v,
                                                        const ushort_t* __restrict__ rs,
                                                        const ushort_t* __restrict__ cs,
                                                        const ushort_t* __restrict__ vf,
                                                        float* __restrict__ out,
                                                        float* __restrict__ pp1) {
  __shared__ ushort_t buf[2][16384];   // 2 x 32 KB, 8 j-records of 4 KB each
  const int bid = blockIdx.x;
  const int jc = bid & 1, pg = (bid >> 1) & 15, bh = bid >> 5;
  const int b = bh >> 3, H = bh & 7;
  const int t = threadIdx.x, wv = t >> 6, l = t & 63;
  const int row = l & 15, quad = l >> 4;
  const int h = pg * 4 + wv;
  const ushort_t* rsl = rs + (size_t)bh * 262144 + (size_t)h * 4096;   // [w][i]
  const ushort_t* csl = cs + (size_t)bh * 262144 + (size_t)h * 4096;   // [b][a]
  const ushort_t* vchunk = vf + (size_t)bh * 131072 + (size_t)jc * 65536;

  bf16x8 rf[2][4];
#pragma unroll
  for (int nf = 0; nf < 4; nf++)
#pragma unroll
    for (int kc = 0; kc < 2; kc++)
      rf[kc][nf] = *(const bf16x8*)&rsl[(size_t)(nf * 16 + row) * 64 + kc * 32 + quad * 8];

  f32x4 acc[2][4];
#pragma unroll
  for (int i = 0; i < 2; i++)
#pragma unroll
    for (int j = 0; j < 4; j++) acc[i][j] = (f32x4){0.f, 0.f, 0.f, 0.f};

#pragma unroll
  for (int jj = 0; jj < 8; jj++)
    gld16(&vchunk[(size_t)jj * 2048 + wv * 512 + l * 8], &buf[0][jj * 2048 + wv * 512]);
  __syncthreads();

  for (int ph = 0; ph < 4; ph++) {
    const ushort_t* bcur = buf[ph & 1];
    if (ph < 3) {
#pragma unroll
      for (int jj = 0; jj < 8; jj++)
        gld16(&vchunk[(size_t)((ph + 1) * 8 + jj) * 2048 + wv * 512 + l * 8],
              &buf[(ph + 1) & 1][jj * 2048 + wv * 512]);
    }
    float cv[8][4];
#pragma unroll
    for (int nf = 0; nf < 4; nf++) {
      uint4 u = *(const uint4*)&csl[(size_t)(nf * 16 + row) * 64 + jc * 32 + ph * 8];
      cv[0][nf] = bflo(u.x); cv[1][nf] = bfhi(u.x);
      cv[2][nf] = bflo(u.y); cv[3][nf] = bfhi(u.y);
      cv[4][nf] = bflo(u.z); cv[5][nf] = bfhi(u.z);
      cv[6][nf] = bflo(u.w); cv[7][nf] = bfhi(u.w);
    }
#pragma unroll
    for (int jj = 0; jj < 8; jj++) {
      bf16x8 af0[2], af1[2];
#pragma unroll
      for (int mf = 0; mf < 2; mf++) {
        af0[mf] = *(const bf16x8*)&bcur[jj * 2048 + (0 + mf) * 512 + l * 8];
        af1[mf] = *(const bf16x8*)&bcur[jj * 2048 + (2 + mf) * 512 + l * 8];
      }
#pragma unroll
      for (int mf = 0; mf < 2; mf++)
#pragma unroll
        for (int nf = 0; nf < 4; nf++) {
          f32x4 tt = (f32x4){0.f, 0.f, 0.f, 0.f};
          tt = mfma16(af0[mf], rf[0][nf], tt);
          tt = mfma16(af1[mf], rf[1][nf], tt);
          acc[mf][nf] += tt * cv[jj][nf];
        }
    }
    __syncthreads();
  }

  if (jc == 0) {
    const float* pv = P_v + (size_t)bh * 131072 + h * 64;
    float* ob = out + ((size_t)b * 256 + H * 32) * 4096 + h * 64;
#pragma unroll
    for (int mf = 0; mf < 2; mf++)
#pragma unroll
      for (int nf = 0; nf < 4; nf++)
#pragma unroll
        for (int reg = 0; reg < 4; reg++) {
          int d = mf * 16 + quad * 4 + reg;
          int wc = nf * 16 + row;
          ob[(size_t)d * 4096 + wc] = acc[mf][nf][reg] + pv[(size_t)d * 4096 + wc];
        }
  } else {
    float* ob = pp1 + (size_t)bh * 131072 + h * 64;
#pragma unroll
    for (int mf = 0; mf < 2; mf++)
#pragma unroll
      for (int nf = 0; nf < 4; nf++)
#pragma unroll
        for (int reg = 0; reg < 4; reg++) {
          int d = mf * 16 + quad * 4 + reg;
          int wc = nf * 16 + row;
          ob[(size_t)d * 4096 + wc] = acc[mf][nf][reg];
        }
  }
}

// ---------------- sum_out: out += Pp1 (same flat order)
__global__ __launch_bounds__(256) void sum_out(float* __restrict__ out,
                                               const float* __restrict__ pp1) {
  const int idx = (blockIdx.x * 256 + threadIdx.x) * 4;
  float4 a = *(const float4*)&out[idx];
  float4 b = *(const float4*)&pp1[idx];
  a.x += b.x; a.y += b.y; a.z += b.z; a.w += b.w;
  *(float4*)&out[idx] = a;
}

extern "C" void kernel_launch(void* const* d_in, const int* in_sizes, int n_in,
                              void* d_out, int out_size, void* d_ws, size_t ws_size,
                              hipStream_t stream) {
  const float* x = (const float*)d_in[0];
  const float* w = (const float*)d_in[1];
  float* out = (float*)d_out;
  float* ws = (float*)d_ws;
  float* P_v = ws;                                  //  2,097,152 fu
  ushort_t* Rs  = (ushort_t*)(ws + 2097152);        //  2,097,152 fu
  ushort_t* Cs  = (ushort_t*)(ws + 4194304);        //  2,097,152 fu
  ushort_t* Vf  = (ushort_t*)(ws + 6291456);        //  1,048,576 fu
  ushort_t* Qr  = (ushort_t*)(ws + 7340032);        //  1,048,576 fu
  ushort_t* Kr  = (ushort_t*)(ws + 8388608);        //  1,048,576 fu
  ushort_t* Qc  = (ushort_t*)(ws + 9437184);        //  1,048,576 fu
  ushort_t* Kc  = (ushort_t*)(ws + 10485760);       //  1,048,576 fu
  ushort_t* Wf  = (ushort_t*)(ws + 11534336);       //    163,840 fu
  ushort_t* Xtf = (ushort_t*)(ws + 11698176);       //  1,048,576 fu
  float* Pp1 = ws + 12746752;                       //  2,097,152 fu

  prep<<<592, 256, 0, stream>>>(x, w, Xtf, Wf);
  proj_mfma_v3<<<dim3(32, 10, 2), 256, 0, stream>>>(Wf, Xtf, Qr, Kr, Qc, Kc, P_v);
  mid<<<640, 256, 0, stream>>>(Qr, Kr, Qc, Kc, Rs, Cs, P_v, Vf);
  attn_apply_v4<<<512, 256, 0, stream>>>(P_v, Rs, Cs, Vf, out, Pp1);
  sum_out<<<2048, 256, 0, stream>>>(out, Pp1);
}